// Round 2
// baseline (1799.590 us; speedup 1.0000x reference)
//
#include <hip/hip_runtime.h>

#define NN 100000
#define EE 1600000
#define DD 128
#define FFD 512
#define EPSV 1e-5f

// ---------------- small utility kernels ----------------

__global__ __launch_bounds__(256) void k_zero_stats(float* s1, float* s2) {
    int t = threadIdx.x;
    s1[t] = 0.f;   // 256 floats: sum[128], sumsq[128]
    s2[t] = 0.f;
}

__global__ __launch_bounds__(256) void k_init_deg(float* deg) {
    int i = blockIdx.x * 256 + threadIdx.x;
    if (i < NN) deg[i] = 1.0f;   // self-loop weight
}

__global__ __launch_bounds__(256) void k_edge_deg(const int* __restrict__ ei,
                                                  const float* __restrict__ ew,
                                                  float* __restrict__ deg) {
    int e = blockIdx.x * 256 + threadIdx.x;
    if (e < EE) {
        int dst = ei[EE + e];
        atomicAdd(&deg[dst], ew[e]);
    }
}

__global__ __launch_bounds__(256) void k_dinv(const float* __restrict__ deg,
                                              float* __restrict__ dinv) {
    int i = blockIdx.x * 256 + threadIdx.x;
    if (i < NN) dinv[i] = rsqrtf(deg[i]);   // deg >= 1 always
}

// ---------------- h = x @ W  (W staged in LDS) ----------------

__global__ __launch_bounds__(256) void k_xw(const float* __restrict__ x,
                                            const float* __restrict__ W,
                                            float* __restrict__ h) {
    __shared__ float wt[DD][DD];    // 64 KB
    __shared__ float xt[16][DD];    // 8 KB
    int t = threadIdx.x;
    int row0 = blockIdx.x * 16;

    for (int i = t; i < DD * DD; i += 256) wt[0][i] = W[i];
    for (int i = t; i < 16 * DD; i += 256) xt[0][i] = x[(long)row0 * DD + i];
    __syncthreads();

    int c = t & 127;
    int rbase = (t >> 7) * 8;
    float acc[8];
#pragma unroll
    for (int rr = 0; rr < 8; ++rr) acc[rr] = 0.f;

    for (int k = 0; k < DD; k += 4) {
        float4 xv[8];
#pragma unroll
        for (int rr = 0; rr < 8; ++rr)
            xv[rr] = *reinterpret_cast<const float4*>(&xt[rbase + rr][k]);
#pragma unroll
        for (int kk = 0; kk < 4; ++kk) {
            float wv = wt[k + kk][c];
#pragma unroll
            for (int rr = 0; rr < 8; ++rr)
                acc[rr] = fmaf(reinterpret_cast<const float*>(&xv[rr])[kk], wv, acc[rr]);
        }
    }
#pragma unroll
    for (int rr = 0; rr < 8; ++rr)
        h[(long)(row0 + rbase + rr) * DD + c] = acc[rr];
}

// ---------------- y = x + dinv^2 * h + b ----------------

__global__ __launch_bounds__(256) void k_y_init(const float* __restrict__ x,
                                                const float* __restrict__ h,
                                                const float* __restrict__ dinv,
                                                const float* __restrict__ b,
                                                float* __restrict__ y) {
    long i = (long)blockIdx.x * 256 + threadIdx.x;
    int node = (int)(i >> 7);
    int c = (int)(i & 127);
    float dv = dinv[node];
    y[i] = x[i] + dv * dv * h[i] + b[c];
}

// ---------------- edge scatter: y[dst] += norm * h[src] ----------------

__global__ __launch_bounds__(256) void k_scatter(const int* __restrict__ ei,
                                                 const float* __restrict__ ew,
                                                 const float* __restrict__ dinv,
                                                 const float* __restrict__ h,
                                                 float* __restrict__ y) {
    int t = threadIdx.x;
    long e = (long)blockIdx.x * 2 + (t >> 7);
    int d = t & 127;
    int src = ei[e];
    int dst = ei[EE + e];
    float nrm = dinv[src] * ew[e] * dinv[dst];
    atomicAdd(&y[(long)dst * DD + d], nrm * h[(long)src * DD + d]);
}

// ---------------- BN stats: per-column sum & sumsq ----------------

__global__ __launch_bounds__(256) void k_bn_stats(const float* __restrict__ v,
                                                  float* __restrict__ stats) {
    __shared__ float red[256];
    int t = threadIdx.x;
    int c = t & 127;
    int half = t >> 7;
    int r0 = blockIdx.x * 256 + half;
    float s = 0.f, q = 0.f;
    for (int j = 0; j < 128; ++j) {
        int r = r0 + 2 * j;
        if (r < NN) {
            float val = v[(long)r * DD + c];
            s += val;
            q += val * val;
        }
    }
    red[t] = s;
    __syncthreads();
    if (half == 0) atomicAdd(&stats[c], red[c] + red[c + 128]);
    __syncthreads();
    red[t] = q;
    __syncthreads();
    if (half == 0) atomicAdd(&stats[128 + c], red[c] + red[c + 128]);
}

__global__ __launch_bounds__(128) void k_bn_fin(const float* __restrict__ stats,
                                                const float* __restrict__ gamma,
                                                const float* __restrict__ beta,
                                                float* __restrict__ ac) {
    int c = threadIdx.x;
    float mu = stats[c] * (1.0f / NN);
    float var = stats[128 + c] * (1.0f / NN) - mu * mu;
    float a = gamma[c] * rsqrtf(var + EPSV);
    ac[c] = a;
    ac[128 + c] = beta[c] - mu * a;
}

__global__ __launch_bounds__(256) void k_affine(float* __restrict__ v,
                                                const float* __restrict__ ac) {
    long i = (long)blockIdx.x * 256 + threadIdx.x;
    int c = (int)(i & 127);
    v[i] = ac[c] * v[i] + ac[128 + c];
}

// ---------------- fused MLP: out = x1 + relu(x1@W1+b1)@W2 + b2, + BN2 stats ----------------
// NOTE: x1 may alias out — each block reads only its own 16 rows into LDS
// before writing those same rows, so in-place is safe.

__global__ __launch_bounds__(256) void k_mlp(const float* __restrict__ x1,
                                             const float* __restrict__ W1,
                                             const float* __restrict__ b1,
                                             const float* __restrict__ W2,
                                             const float* __restrict__ b2,
                                             float* __restrict__ out,
                                             float* __restrict__ stats2) {
    __shared__ float wt[DD][DD];    // 64 KB (W1 chunk, then W2 chunk)
    __shared__ float x1t[16][DD];   // 8 KB
    __shared__ float ht[16][DD];    // 8 KB
    int t = threadIdx.x;
    int row0 = blockIdx.x * 16;

    for (int i = t; i < 16 * DD; i += 256) x1t[0][i] = x1[(long)row0 * DD + i];

    int c = t & 127;
    int rbase = (t >> 7) * 8;
    float acc[8];
#pragma unroll
    for (int rr = 0; rr < 8; ++rr) acc[rr] = 0.f;

    for (int ch = 0; ch < 4; ++ch) {
        __syncthreads();   // protect wt/ht reuse from previous chunk (and x1t load at ch=0)
        for (int i = t; i < DD * DD; i += 256) {
            int k = i >> 7, f = i & 127;
            wt[k][f] = W1[(long)k * FFD + ch * 128 + f];
        }
        __syncthreads();

        // hidden chunk = relu(x1 @ W1chunk + b1chunk)
        float hacc[8];
        float b1v = b1[ch * 128 + c];
#pragma unroll
        for (int rr = 0; rr < 8; ++rr) hacc[rr] = b1v;
        for (int k = 0; k < DD; k += 4) {
            float4 xv[8];
#pragma unroll
            for (int rr = 0; rr < 8; ++rr)
                xv[rr] = *reinterpret_cast<const float4*>(&x1t[rbase + rr][k]);
#pragma unroll
            for (int kk = 0; kk < 4; ++kk) {
                float wv = wt[k + kk][c];
#pragma unroll
                for (int rr = 0; rr < 8; ++rr)
                    hacc[rr] = fmaf(reinterpret_cast<const float*>(&xv[rr])[kk], wv, hacc[rr]);
            }
        }
#pragma unroll
        for (int rr = 0; rr < 8; ++rr) ht[rbase + rr][c] = fmaxf(hacc[rr], 0.f);
        __syncthreads();

        // load W2 chunk (contiguous 16384 floats)
        for (int i = t; i < DD * DD; i += 256) wt[0][i] = W2[(long)ch * DD * DD + i];
        __syncthreads();

        // acc += hidden @ W2chunk
        for (int k = 0; k < DD; k += 4) {
            float4 hv[8];
#pragma unroll
            for (int rr = 0; rr < 8; ++rr)
                hv[rr] = *reinterpret_cast<const float4*>(&ht[rbase + rr][k]);
#pragma unroll
            for (int kk = 0; kk < 4; ++kk) {
                float wv = wt[k + kk][c];
#pragma unroll
                for (int rr = 0; rr < 8; ++rr)
                    acc[rr] = fmaf(reinterpret_cast<const float*>(&hv[rr])[kk], wv, acc[rr]);
            }
        }
    }

    // epilogue: z = x1 + x2 + b2; write out; BN2 partial stats
    float b2v = b2[c];
    float s = 0.f, q = 0.f;
#pragma unroll
    for (int rr = 0; rr < 8; ++rr) {
        float z = x1t[rbase + rr][c] + acc[rr] + b2v;
        out[(long)(row0 + rbase + rr) * DD + c] = z;
        s += z;
        q += z * z;
    }
    __syncthreads();
    float* red = &ht[0][0];
    red[t] = s;
    __syncthreads();
    if (t < 128) atomicAdd(&stats2[c], red[c] + red[c + 128]);
    __syncthreads();
    red[t] = q;
    __syncthreads();
    if (t < 128) atomicAdd(&stats2[128 + c], red[c] + red[c + 128]);
}

// ---------------- launch ----------------

extern "C" void kernel_launch(void* const* d_in, const int* in_sizes, int n_in,
                              void* d_out, int out_size, void* d_ws, size_t ws_size,
                              hipStream_t stream) {
    const float* x        = (const float*)d_in[0];
    const int*   ei       = (const int*)d_in[1];   // int64 in ref -> int32 on device
    const float* ew       = (const float*)d_in[2];
    const float* W        = (const float*)d_in[3];
    const float* b        = (const float*)d_in[4];
    const float* gamma    = (const float*)d_in[5];
    const float* beta     = (const float*)d_in[6];
    const float* W1       = (const float*)d_in[7];
    const float* b1       = (const float*)d_in[8];
    const float* W2       = (const float*)d_in[9];
    const float* b2       = (const float*)d_in[10];
    float* out = (float*)d_out;
    float* ws  = (float*)d_ws;

    float* deg    = ws;                 // NN
    float* dinv   = ws + NN;            // NN
    float* stats1 = ws + 2 * NN;        // 256 floats
    float* ac1    = stats1 + 256;       // 256 floats
    float* stats2 = ac1 + 256;          // 256 floats
    float* ac2    = stats2 + 256;       // 256 floats
    float* h      = ws + 2 * NN + 1024; // NN*DD
    float* y      = out;                // alias: x1 lives in d_out (in-place safe)

    k_zero_stats<<<1, 256, 0, stream>>>(stats1, stats2);
    k_init_deg<<<(NN + 255) / 256, 256, 0, stream>>>(deg);
    k_edge_deg<<<EE / 256, 256, 0, stream>>>(ei, ew, deg);
    k_dinv<<<(NN + 255) / 256, 256, 0, stream>>>(deg, dinv);
    k_xw<<<NN / 16, 256, 0, stream>>>(x, W, h);
    k_y_init<<<(NN * DD) / 256, 256, 0, stream>>>(x, h, dinv, b, y);
    k_scatter<<<EE / 2, 256, 0, stream>>>(ei, ew, dinv, h, y);
    k_bn_stats<<<(NN + 255) / 256, 256, 0, stream>>>(y, stats1);
    k_bn_fin<<<1, 128, 0, stream>>>(stats1, gamma, beta, ac1);
    k_affine<<<(NN * DD) / 256, 256, 0, stream>>>(y, ac1);
    k_mlp<<<NN / 16, 256, 0, stream>>>(y, W1, b1, W2, b2, out, stats2);
    k_bn_fin<<<1, 128, 0, stream>>>(stats2, gamma, beta, ac2);
    k_affine<<<(NN * DD) / 256, 256, 0, stream>>>(out, ac2);
}

// Round 3
// 1629.332 us; speedup vs baseline: 1.1045x; 1.1045x over previous
//
#include <hip/hip_runtime.h>

#define NN 100000
#define EE 1600000
#define DD 128
#define FFD 512
#define EPSV 1e-5f

typedef __attribute__((ext_vector_type(8))) short bf16x8;
typedef __attribute__((ext_vector_type(4))) float f32x4;

__device__ __forceinline__ ushort f2b(float f) {          // fp32 -> bf16 RNE
    uint u = __float_as_uint(f);
    return (ushort)((u + 0x7FFF + ((u >> 16) & 1)) >> 16);
}
__device__ __forceinline__ float b2f(ushort u) {
    return __uint_as_float(((uint)u) << 16);
}

// ---------------- small utility kernels ----------------

__global__ __launch_bounds__(256) void k_zero_stats(float* s1, float* s2) {
    int t = threadIdx.x;
    s1[t] = 0.f;
    s2[t] = 0.f;
}

__global__ __launch_bounds__(256) void k_init_deg(float* deg) {
    int i = blockIdx.x * 256 + threadIdx.x;
    if (i < NN) deg[i] = 1.0f;   // self-loop
}

__global__ __launch_bounds__(256) void k_edge_deg(const int* __restrict__ ei,
                                                  const float* __restrict__ ew,
                                                  float* __restrict__ deg) {
    int e = blockIdx.x * 256 + threadIdx.x;
    if (e < EE) atomicAdd(&deg[ei[EE + e]], ew[e]);
}

__global__ __launch_bounds__(256) void k_dinv(const float* __restrict__ deg,
                                              float* __restrict__ dinv) {
    int i = blockIdx.x * 256 + threadIdx.x;
    if (i < NN) dinv[i] = rsqrtf(deg[i]);
}

// ---------------- one-time weight transpose + bf16 convert ----------------
// WTb[n][k]=W[k][n] (128x128); W1Tb[f][k]=W1[k][f] (512x128); W2Tb[j][f]=W2[f][j] (128x512)

__global__ __launch_bounds__(256) void k_wcvt(const float* __restrict__ W,
                                              const float* __restrict__ W1,
                                              const float* __restrict__ W2,
                                              ushort* __restrict__ WTb,
                                              ushort* __restrict__ W1Tb,
                                              ushort* __restrict__ W2Tb) {
    int i = blockIdx.x * 256 + threadIdx.x;
    if (i < 16384) {
        int n = i >> 7, k = i & 127;
        WTb[i] = f2b(W[k * 128 + n]);
    } else if (i < 16384 + 65536) {
        int j = i - 16384;
        int f = j >> 7, k = j & 127;
        W1Tb[j] = f2b(W1[k * 512 + f]);
    } else {
        int j = i - 16384 - 65536;
        int jj = j >> 9, f = j & 511;
        W2Tb[j] = f2b(W2[f * 128 + jj]);
    }
}

// ---------------- h = x @ W via MFMA, h stored bf16 ----------------
// block: 64 rows, 256 threads = 4 waves, each wave 16 rows x 128 cols.

__global__ __launch_bounds__(256) void k_xw(const float* __restrict__ x,
                                            const ushort* __restrict__ WTb,
                                            ushort* __restrict__ hb) {
    __shared__ __align__(16) ushort xt[64][136];
    __shared__ __align__(16) ushort wt[128][136];
    int t = threadIdx.x;
    int row0 = blockIdx.x * 64;

    // stage W^T (16384 ushorts = 2048 uint4)
    for (int i = t; i < 2048; i += 256) {
        int r = i >> 4, c8 = (i & 15) << 3;
        *(uint4*)&wt[r][c8] = ((const uint4*)WTb)[i];
    }
    // stage x tile -> bf16 (64x128, 2048 float4 groups)
    for (int i = t; i < 2048; i += 256) {
        int r = i >> 5, c4 = (i & 31) << 2;
        int gr = row0 + r;
        float4 v = make_float4(0.f, 0.f, 0.f, 0.f);
        if (gr < NN) v = ((const float4*)x)[(long)gr * 32 + (i & 31)];
        ushort4 o;
        o.x = f2b(v.x); o.y = f2b(v.y); o.z = f2b(v.z); o.w = f2b(v.w);
        *(ushort4*)&xt[r][c4] = o;
    }
    __syncthreads();

    int wv = t >> 6, l = t & 63;
    int lr = l & 15, lg = l >> 4;
    int wrow = wv * 16;

    f32x4 acc[8];
    f32x4 z4 = {0.f, 0.f, 0.f, 0.f};
#pragma unroll
    for (int nt = 0; nt < 8; ++nt) acc[nt] = z4;

#pragma unroll
    for (int ks = 0; ks < 4; ++ks) {
        bf16x8 af = *(const bf16x8*)&xt[wrow + lr][ks * 32 + lg * 8];
#pragma unroll
        for (int nt = 0; nt < 8; ++nt) {
            bf16x8 bf = *(const bf16x8*)&wt[nt * 16 + lr][ks * 32 + lg * 8];
            acc[nt] = __builtin_amdgcn_mfma_f32_16x16x32_bf16(af, bf, acc[nt], 0, 0, 0);
        }
    }

    // C/D layout: col = lane&15, row = (lane>>4)*4 + reg
#pragma unroll
    for (int nt = 0; nt < 8; ++nt) {
#pragma unroll
        for (int rg = 0; rg < 4; ++rg) {
            int r = row0 + wrow + lg * 4 + rg;
            if (r < NN) hb[(long)r * 128 + nt * 16 + lr] = f2b(acc[nt][rg]);
        }
    }
}

// ---------------- y = x + dinv^2*h + b (h bf16) ----------------

__global__ __launch_bounds__(256) void k_y_init(const float* __restrict__ x,
                                                const ushort* __restrict__ hb,
                                                const float* __restrict__ dinv,
                                                const float* __restrict__ b,
                                                float* __restrict__ y) {
    long i = (long)blockIdx.x * 256 + threadIdx.x;   // index in float4 units
    int node = (int)(i >> 5);
    int c4i = (int)(i & 31);
    float dv = dinv[node];
    float s = dv * dv;
    float4 xv = ((const float4*)x)[i];
    ushort4 hv = ((const ushort4*)hb)[i];
    float4 bv = ((const float4*)b)[c4i];
    float4 o;
    o.x = xv.x + s * b2f(hv.x) + bv.x;
    o.y = xv.y + s * b2f(hv.y) + bv.y;
    o.z = xv.z + s * b2f(hv.z) + bv.z;
    o.w = xv.w + s * b2f(hv.w) + bv.w;
    ((float4*)y)[i] = o;
}

// ---------------- edge scatter: y[dst] += norm * h[src] (h bf16) ----------------
// 1 wave per edge, lane handles 2 features.

__global__ __launch_bounds__(256) void k_scatter(const int* __restrict__ ei,
                                                 const float* __restrict__ ew,
                                                 const float* __restrict__ dinv,
                                                 const ushort* __restrict__ hb,
                                                 float* __restrict__ y) {
    int t = threadIdx.x;
    long e = (long)blockIdx.x * 4 + (t >> 6);
    int l = t & 63;
    int src = ei[e];
    int dst = ei[EE + e];
    float nrm = dinv[src] * ew[e] * dinv[dst];
    uint hv = ((const uint*)hb)[(long)src * 64 + l];
    float h0 = b2f((ushort)(hv & 0xFFFF));
    float h1 = b2f((ushort)(hv >> 16));
    atomicAdd(&y[(long)dst * 128 + 2 * l], nrm * h0);
    atomicAdd(&y[(long)dst * 128 + 2 * l + 1], nrm * h1);
}

// ---------------- BN stats ----------------

__global__ __launch_bounds__(256) void k_bn_stats(const float* __restrict__ v,
                                                  float* __restrict__ stats) {
    __shared__ float red[256];
    int t = threadIdx.x;
    int c = t & 127;
    int half = t >> 7;
    int r0 = blockIdx.x * 256 + half;
    float s = 0.f, q = 0.f;
    for (int j = 0; j < 128; ++j) {
        int r = r0 + 2 * j;
        if (r < NN) {
            float val = v[(long)r * DD + c];
            s += val;
            q += val * val;
        }
    }
    red[t] = s;
    __syncthreads();
    if (half == 0) atomicAdd(&stats[c], red[c] + red[c + 128]);
    __syncthreads();
    red[t] = q;
    __syncthreads();
    if (half == 0) atomicAdd(&stats[128 + c], red[c] + red[c + 128]);
}

__global__ __launch_bounds__(128) void k_bn_fin(const float* __restrict__ stats,
                                                const float* __restrict__ gamma,
                                                const float* __restrict__ beta,
                                                float* __restrict__ ac) {
    int c = threadIdx.x;
    float mu = stats[c] * (1.0f / NN);
    float var = stats[128 + c] * (1.0f / NN) - mu * mu;
    float a = gamma[c] * rsqrtf(var + EPSV);
    ac[c] = a;
    ac[128 + c] = beta[c] - mu * a;
}

__global__ __launch_bounds__(256) void k_affine(float* __restrict__ v,
                                                const float* __restrict__ ac) {
    long i = (long)blockIdx.x * 256 + threadIdx.x;   // float4 units
    int c4i = (int)(i & 31);
    float4 a = ((const float4*)ac)[c4i];
    float4 cc = ((const float4*)(ac + 128))[c4i];
    float4 v4 = ((float4*)v)[i];
    v4.x = a.x * v4.x + cc.x;
    v4.y = a.y * v4.y + cc.y;
    v4.z = a.z * v4.z + cc.z;
    v4.w = a.w * v4.w + cc.w;
    ((float4*)v)[i] = v4;
}

// ---------------- fused MLP via MFMA ----------------
// x1 = ac1-affine(y) staged bf16; out = x1 + relu(x1@W1+b1)@W2 + b2 (in-place on y=out);
// BN2 stats accumulated. block: 64 rows, 4 waves.

__global__ __launch_bounds__(256) void k_mlp(const float* __restrict__ y,
                                             const float* __restrict__ ac1,
                                             const ushort* __restrict__ W1Tb,
                                             const float* __restrict__ b1,
                                             const ushort* __restrict__ W2Tb,
                                             const float* __restrict__ b2,
                                             float* __restrict__ out,
                                             float* __restrict__ stats2) {
    __shared__ __align__(16) ushort xt[64][136];
    __shared__ __align__(16) ushort ht[64][136];
    __shared__ __align__(16) ushort wc[128][136];
    __shared__ float redS[4][128];
    __shared__ float redQ[4][128];
    int t = threadIdx.x;
    int row0 = blockIdx.x * 64;

    // stage x1 = a*y + c  -> bf16
    for (int i = t; i < 2048; i += 256) {
        int r = i >> 5, c4i = i & 31;
        int gr = row0 + r;
        float4 v = make_float4(0.f, 0.f, 0.f, 0.f);
        if (gr < NN) v = ((const float4*)y)[(long)gr * 32 + c4i];
        float4 a = ((const float4*)ac1)[c4i];
        float4 cc = ((const float4*)(ac1 + 128))[c4i];
        ushort4 o;
        o.x = f2b(a.x * v.x + cc.x);
        o.y = f2b(a.y * v.y + cc.y);
        o.z = f2b(a.z * v.z + cc.z);
        o.w = f2b(a.w * v.w + cc.w);
        *(ushort4*)&xt[r][c4i << 2] = o;
    }

    int wv = t >> 6, l = t & 63;
    int lr = l & 15, lg = l >> 4;
    int wrow = wv * 16;

    f32x4 acc[8];
    f32x4 z4 = {0.f, 0.f, 0.f, 0.f};
#pragma unroll
    for (int nt = 0; nt < 8; ++nt) acc[nt] = z4;

    for (int ch = 0; ch < 4; ++ch) {
        __syncthreads();   // wc reuse (and xt staging at ch=0)
        // stage W1T chunk (rows ch*128..+127 contiguous): 2048 uint4
        for (int i = t; i < 2048; i += 256) {
            int r = i >> 4, c8 = (i & 15) << 3;
            *(uint4*)&wc[r][c8] = ((const uint4*)W1Tb)[ch * 2048 + i];
        }
        __syncthreads();

        // GEMM1: hidden = relu(x1 @ W1c + b1c)
        f32x4 hacc[8];
#pragma unroll
        for (int nt = 0; nt < 8; ++nt) hacc[nt] = z4;
#pragma unroll
        for (int ks = 0; ks < 4; ++ks) {
            bf16x8 af = *(const bf16x8*)&xt[wrow + lr][ks * 32 + lg * 8];
#pragma unroll
            for (int nt = 0; nt < 8; ++nt) {
                bf16x8 bf = *(const bf16x8*)&wc[nt * 16 + lr][ks * 32 + lg * 8];
                hacc[nt] = __builtin_amdgcn_mfma_f32_16x16x32_bf16(af, bf, hacc[nt], 0, 0, 0);
            }
        }
#pragma unroll
        for (int nt = 0; nt < 8; ++nt) {
            float b1v = b1[ch * 128 + nt * 16 + lr];
#pragma unroll
            for (int rg = 0; rg < 4; ++rg) {
                float hval = fmaxf(hacc[nt][rg] + b1v, 0.f);
                ht[wrow + lg * 4 + rg][nt * 16 + lr] = f2b(hval);  // wave-private rows
            }
        }
        __syncthreads();   // all waves done reading wc (GEMM1)

        // stage W2T chunk: row j (128), cols ch*128..+127 (strided rows of 512)
        for (int i = t; i < 2048; i += 256) {
            int r = i >> 4, c8i = i & 15;
            *(uint4*)&wc[r][c8i << 3] = ((const uint4*)W2Tb)[r * 64 + ch * 16 + c8i];
        }
        __syncthreads();

        // GEMM2: acc += hidden @ W2c
#pragma unroll
        for (int ks = 0; ks < 4; ++ks) {
            bf16x8 af = *(const bf16x8*)&ht[wrow + lr][ks * 32 + lg * 8];
#pragma unroll
            for (int nt = 0; nt < 8; ++nt) {
                bf16x8 bf = *(const bf16x8*)&wc[nt * 16 + lr][ks * 32 + lg * 8];
                acc[nt] = __builtin_amdgcn_mfma_f32_16x16x32_bf16(af, bf, acc[nt], 0, 0, 0);
            }
        }
    }

    // epilogue: z = x1 + x2 + b2; store; BN2 partial stats
#pragma unroll
    for (int nt = 0; nt < 8; ++nt) {
        float b2v = b2[nt * 16 + lr];
        float s = 0.f, q = 0.f;
#pragma unroll
        for (int rg = 0; rg < 4; ++rg) {
            int r = row0 + wrow + lg * 4 + rg;
            float x1v = b2f(xt[wrow + lg * 4 + rg][nt * 16 + lr]);
            float z = x1v + acc[nt][rg] + b2v;
            if (r < NN) {
                out[(long)r * 128 + nt * 16 + lr] = z;
                s += z;
                q += z * z;
            }
        }
        s += __shfl_xor(s, 16); s += __shfl_xor(s, 32);
        q += __shfl_xor(q, 16); q += __shfl_xor(q, 32);
        if (lg == 0) { redS[wv][nt * 16 + lr] = s; redQ[wv][nt * 16 + lr] = q; }
    }
    __syncthreads();
    if (t < 128) {
        float S = redS[0][t] + redS[1][t] + redS[2][t] + redS[3][t];
        float Q = redQ[0][t] + redQ[1][t] + redQ[2][t] + redQ[3][t];
        atomicAdd(&stats2[t], S);
        atomicAdd(&stats2[128 + t], Q);
    }
}

// ---------------- launch ----------------

extern "C" void kernel_launch(void* const* d_in, const int* in_sizes, int n_in,
                              void* d_out, int out_size, void* d_ws, size_t ws_size,
                              hipStream_t stream) {
    const float* x     = (const float*)d_in[0];
    const int*   ei    = (const int*)d_in[1];
    const float* ew    = (const float*)d_in[2];
    const float* W     = (const float*)d_in[3];
    const float* b     = (const float*)d_in[4];
    const float* gamma = (const float*)d_in[5];
    const float* beta  = (const float*)d_in[6];
    const float* W1    = (const float*)d_in[7];
    const float* b1    = (const float*)d_in[8];
    const float* W2    = (const float*)d_in[9];
    const float* b2    = (const float*)d_in[10];
    float* out = (float*)d_out;
    float* ws  = (float*)d_ws;

    float* deg    = ws;
    float* dinv   = ws + NN;
    float* stats1 = ws + 2 * NN;
    float* ac1    = stats1 + 256;
    float* stats2 = ac1 + 256;
    float* ac2    = stats2 + 256;
    ushort* hb    = (ushort*)(ws + 2 * NN + 1024);   // NN*128 bf16
    ushort* WTb   = hb + (long)NN * 128;             // 16384
    ushort* W1Tb  = WTb + 16384;                     // 65536
    ushort* W2Tb  = W1Tb + 65536;                    // 65536
    float* y      = out;                             // x1 lives in d_out

    int nb = (NN + 63) / 64;   // 1563

    k_zero_stats<<<1, 256, 0, stream>>>(stats1, stats2);
    k_init_deg<<<(NN + 255) / 256, 256, 0, stream>>>(deg);
    k_edge_deg<<<EE / 256, 256, 0, stream>>>(ei, ew, deg);
    k_dinv<<<(NN + 255) / 256, 256, 0, stream>>>(deg, dinv);
    k_wcvt<<<576, 256, 0, stream>>>(W, W1, W2, WTb, W1Tb, W2Tb);
    k_xw<<<nb, 256, 0, stream>>>(x, WTb, hb);
    k_y_init<<<(NN * 32) / 256, 256, 0, stream>>>(x, hb, dinv, b, y);
    k_scatter<<<EE / 4, 256, 0, stream>>>(ei, ew, dinv, hb, y);
    k_bn_stats<<<(NN + 255) / 256, 256, 0, stream>>>(y, stats1);
    k_bn_fin<<<1, 128, 0, stream>>>(stats1, gamma, beta, ac1);
    k_mlp<<<nb, 256, 0, stream>>>(y, ac1, W1Tb, b1, W2Tb, b2, out, stats2);
    k_bn_fin<<<1, 128, 0, stream>>>(stats2, gamma, beta, ac2);
    k_affine<<<(NN * 32) / 256, 256, 0, stream>>>(out, ac2);
}

// Round 4
// 785.808 us; speedup vs baseline: 2.2901x; 2.0734x over previous
//
#include <hip/hip_runtime.h>

#define NN 100000
#define EE 1600000
#define DD 128
#define FFD 512
#define EPSV 1e-5f

typedef __attribute__((ext_vector_type(8))) short bf16x8;
typedef __attribute__((ext_vector_type(4))) float f32x4;

__device__ __forceinline__ ushort f2b(float f) {          // fp32 -> bf16 RNE
    uint u = __float_as_uint(f);
    return (ushort)((u + 0x7FFF + ((u >> 16) & 1)) >> 16);
}
__device__ __forceinline__ float b2f(ushort u) {
    return __uint_as_float(((uint)u) << 16);
}

// ---------------- small utility kernels ----------------

__global__ __launch_bounds__(256) void k_zero_stats(float* s1, float* s2) {
    int t = threadIdx.x;
    s1[t] = 0.f;
    s2[t] = 0.f;
}

__global__ __launch_bounds__(256) void k_init(float* deg, int* cnt) {
    int i = blockIdx.x * 256 + threadIdx.x;
    if (i < NN) { deg[i] = 1.0f; cnt[i] = 0; }   // self-loop weight 1
}

__global__ __launch_bounds__(256) void k_edge_deg(const int* __restrict__ ei,
                                                  const float* __restrict__ ew,
                                                  float* __restrict__ deg,
                                                  int* __restrict__ cnt) {
    int e = blockIdx.x * 256 + threadIdx.x;
    if (e < EE) {
        int dst = ei[EE + e];
        atomicAdd(&deg[dst], ew[e]);
        atomicAdd(&cnt[dst], 1);
    }
}

__global__ __launch_bounds__(256) void k_dinv(const float* __restrict__ deg,
                                              float* __restrict__ dinv) {
    int i = blockIdx.x * 256 + threadIdx.x;
    if (i < NN) dinv[i] = rsqrtf(deg[i]);
}

// ---------------- exclusive prefix scan of cnt -> start, cursor (1 block) ----------------

__global__ __launch_bounds__(256) void k_scan(const int* __restrict__ cnt,
                                              int* __restrict__ start,
                                              int* __restrict__ cursor) {
    __shared__ int tsum[256];
    int t = threadIdx.x;
    const int CH = (NN + 255) / 256;   // 391
    int lo = t * CH;
    int hi = lo + CH; if (hi > NN) hi = NN; if (lo > NN) lo = NN;
    int s = 0;
    for (int i = lo; i < hi; ++i) s += cnt[i];
    tsum[t] = s;
    __syncthreads();
    int off = 0;
    for (int i = 0; i < t; ++i) off += tsum[i];
    int run = off;
    for (int i = lo; i < hi; ++i) {
        start[i] = run;
        cursor[i] = run;
        run += cnt[i];
    }
    if (t == 255) start[NN] = run;   // == EE
}

// ---------------- fill CSR records (src, norm) bucketed by dst ----------------

__global__ __launch_bounds__(256) void k_fill(const int* __restrict__ ei,
                                              const float* __restrict__ ew,
                                              const float* __restrict__ dinv,
                                              int* __restrict__ cursor,
                                              uint2* __restrict__ csr) {
    int e = blockIdx.x * 256 + threadIdx.x;
    if (e < EE) {
        int src = ei[e];
        int dst = ei[EE + e];
        float nrm = dinv[src] * ew[e] * dinv[dst];
        int pos = atomicAdd(&cursor[dst], 1);
        csr[pos] = make_uint2((uint)src, __float_as_uint(nrm));
    }
}

// ---------------- one-time weight transpose + bf16 convert ----------------

__global__ __launch_bounds__(256) void k_wcvt(const float* __restrict__ W,
                                              const float* __restrict__ W1,
                                              const float* __restrict__ W2,
                                              ushort* __restrict__ WTb,
                                              ushort* __restrict__ W1Tb,
                                              ushort* __restrict__ W2Tb) {
    int i = blockIdx.x * 256 + threadIdx.x;
    if (i < 16384) {
        int n = i >> 7, k = i & 127;
        WTb[i] = f2b(W[k * 128 + n]);
    } else if (i < 16384 + 65536) {
        int j = i - 16384;
        int f = j >> 7, k = j & 127;
        W1Tb[j] = f2b(W1[k * 512 + f]);
    } else {
        int j = i - 16384 - 65536;
        int jj = j >> 9, f = j & 511;
        W2Tb[j] = f2b(W2[f * 128 + jj]);
    }
}

// ---------------- h = x @ W via MFMA, h stored bf16 ----------------

__global__ __launch_bounds__(256) void k_xw(const float* __restrict__ x,
                                            const ushort* __restrict__ WTb,
                                            ushort* __restrict__ hb) {
    __shared__ __align__(16) ushort xt[64][136];
    __shared__ __align__(16) ushort wt[128][136];
    int t = threadIdx.x;
    int row0 = blockIdx.x * 64;

    for (int i = t; i < 2048; i += 256) {
        int r = i >> 4, c8 = (i & 15) << 3;
        *(uint4*)&wt[r][c8] = ((const uint4*)WTb)[i];
    }
    for (int i = t; i < 2048; i += 256) {
        int r = i >> 5, c4 = (i & 31) << 2;
        int gr = row0 + r;
        float4 v = make_float4(0.f, 0.f, 0.f, 0.f);
        if (gr < NN) v = ((const float4*)x)[(long)gr * 32 + (i & 31)];
        ushort4 o;
        o.x = f2b(v.x); o.y = f2b(v.y); o.z = f2b(v.z); o.w = f2b(v.w);
        *(ushort4*)&xt[r][c4] = o;
    }
    __syncthreads();

    int wv = t >> 6, l = t & 63;
    int lr = l & 15, lg = l >> 4;
    int wrow = wv * 16;

    f32x4 acc[8];
    f32x4 z4 = {0.f, 0.f, 0.f, 0.f};
#pragma unroll
    for (int nt = 0; nt < 8; ++nt) acc[nt] = z4;

#pragma unroll
    for (int ks = 0; ks < 4; ++ks) {
        bf16x8 af = *(const bf16x8*)&xt[wrow + lr][ks * 32 + lg * 8];
#pragma unroll
        for (int nt = 0; nt < 8; ++nt) {
            bf16x8 bf = *(const bf16x8*)&wt[nt * 16 + lr][ks * 32 + lg * 8];
            acc[nt] = __builtin_amdgcn_mfma_f32_16x16x32_bf16(af, bf, acc[nt], 0, 0, 0);
        }
    }

#pragma unroll
    for (int nt = 0; nt < 8; ++nt) {
#pragma unroll
        for (int rg = 0; rg < 4; ++rg) {
            int r = row0 + wrow + lg * 4 + rg;
            if (r < NN) hb[(long)r * 128 + nt * 16 + lr] = f2b(acc[nt][rg]);
        }
    }
}

// ---------------- gather: y[n] = x[n] + dinv[n]^2*h[n] + b + sum_e norm*h[src] ----------------
// 1 wave per dst node; lane handles 2 features (via packed bf16 uint).

__global__ __launch_bounds__(256) void k_gather(const float* __restrict__ x,
                                                const ushort* __restrict__ hb,
                                                const float* __restrict__ dinv,
                                                const float* __restrict__ b,
                                                const int* __restrict__ start,
                                                const uint2* __restrict__ csr,
                                                float* __restrict__ y) {
    int t = threadIdx.x;
    int wv = t >> 6, l = t & 63;
    int node = blockIdx.x * 4 + wv;
    if (node >= NN) return;
    int s0 = start[node], s1 = start[node + 1];
    const uint* hbu = (const uint*)hb;
    float acc0 = 0.f, acc1 = 0.f;
    int i = s0;
    // unroll-by-2 to get two h loads in flight
    for (; i + 2 <= s1; i += 2) {
        uint2 r0 = csr[i], r1 = csr[i + 1];
        uint h0 = hbu[(long)(int)r0.x * 64 + l];
        uint h1 = hbu[(long)(int)r1.x * 64 + l];
        float n0 = __uint_as_float(r0.y), n1 = __uint_as_float(r1.y);
        acc0 = fmaf(n0, b2f((ushort)(h0 & 0xFFFF)), acc0);
        acc1 = fmaf(n0, b2f((ushort)(h0 >> 16)), acc1);
        acc0 = fmaf(n1, b2f((ushort)(h1 & 0xFFFF)), acc0);
        acc1 = fmaf(n1, b2f((ushort)(h1 >> 16)), acc1);
    }
    if (i < s1) {
        uint2 r0 = csr[i];
        uint h0 = hbu[(long)(int)r0.x * 64 + l];
        float n0 = __uint_as_float(r0.y);
        acc0 = fmaf(n0, b2f((ushort)(h0 & 0xFFFF)), acc0);
        acc1 = fmaf(n0, b2f((ushort)(h0 >> 16)), acc1);
    }
    float dv = dinv[node];
    float sl = dv * dv;
    uint hs = hbu[(long)node * 64 + l];
    float2 xv = ((const float2*)x)[(long)node * 64 + l];
    float2 bv = ((const float2*)b)[l];
    float o0 = xv.x + sl * b2f((ushort)(hs & 0xFFFF)) + bv.x + acc0;
    float o1 = xv.y + sl * b2f((ushort)(hs >> 16)) + bv.y + acc1;
    ((float2*)y)[(long)node * 64 + l] = make_float2(o0, o1);
}

// ---------------- BN stats ----------------

__global__ __launch_bounds__(256) void k_bn_stats(const float* __restrict__ v,
                                                  float* __restrict__ stats) {
    __shared__ float red[256];
    int t = threadIdx.x;
    int c = t & 127;
    int half = t >> 7;
    int r0 = blockIdx.x * 256 + half;
    float s = 0.f, q = 0.f;
    for (int j = 0; j < 128; ++j) {
        int r = r0 + 2 * j;
        if (r < NN) {
            float val = v[(long)r * DD + c];
            s += val;
            q += val * val;
        }
    }
    red[t] = s;
    __syncthreads();
    if (half == 0) atomicAdd(&stats[c], red[c] + red[c + 128]);
    __syncthreads();
    red[t] = q;
    __syncthreads();
    if (half == 0) atomicAdd(&stats[128 + c], red[c] + red[c + 128]);
}

__global__ __launch_bounds__(128) void k_bn_fin(const float* __restrict__ stats,
                                                const float* __restrict__ gamma,
                                                const float* __restrict__ beta,
                                                float* __restrict__ ac) {
    int c = threadIdx.x;
    float mu = stats[c] * (1.0f / NN);
    float var = stats[128 + c] * (1.0f / NN) - mu * mu;
    float a = gamma[c] * rsqrtf(var + EPSV);
    ac[c] = a;
    ac[128 + c] = beta[c] - mu * a;
}

__global__ __launch_bounds__(256) void k_affine(float* __restrict__ v,
                                                const float* __restrict__ ac) {
    long i = (long)blockIdx.x * 256 + threadIdx.x;   // float4 units
    int c4i = (int)(i & 31);
    float4 a = ((const float4*)ac)[c4i];
    float4 cc = ((const float4*)(ac + 128))[c4i];
    float4 v4 = ((float4*)v)[i];
    v4.x = a.x * v4.x + cc.x;
    v4.y = a.y * v4.y + cc.y;
    v4.z = a.z * v4.z + cc.z;
    v4.w = a.w * v4.w + cc.w;
    ((float4*)v)[i] = v4;
}

// ---------------- fused MLP via MFMA ----------------

__global__ __launch_bounds__(256) void k_mlp(const float* __restrict__ y,
                                             const float* __restrict__ ac1,
                                             const ushort* __restrict__ W1Tb,
                                             const float* __restrict__ b1,
                                             const ushort* __restrict__ W2Tb,
                                             const float* __restrict__ b2,
                                             float* __restrict__ out,
                                             float* __restrict__ stats2) {
    __shared__ __align__(16) ushort xt[64][136];
    __shared__ __align__(16) ushort ht[64][136];
    __shared__ __align__(16) ushort wc[128][136];
    __shared__ float redS[4][128];
    __shared__ float redQ[4][128];
    int t = threadIdx.x;
    int row0 = blockIdx.x * 64;

    for (int i = t; i < 2048; i += 256) {
        int r = i >> 5, c4i = i & 31;
        int gr = row0 + r;
        float4 v = make_float4(0.f, 0.f, 0.f, 0.f);
        if (gr < NN) v = ((const float4*)y)[(long)gr * 32 + c4i];
        float4 a = ((const float4*)ac1)[c4i];
        float4 cc = ((const float4*)(ac1 + 128))[c4i];
        ushort4 o;
        o.x = f2b(a.x * v.x + cc.x);
        o.y = f2b(a.y * v.y + cc.y);
        o.z = f2b(a.z * v.z + cc.z);
        o.w = f2b(a.w * v.w + cc.w);
        *(ushort4*)&xt[r][c4i << 2] = o;
    }

    int wv = t >> 6, l = t & 63;
    int lr = l & 15, lg = l >> 4;
    int wrow = wv * 16;

    f32x4 acc[8];
    f32x4 z4 = {0.f, 0.f, 0.f, 0.f};
#pragma unroll
    for (int nt = 0; nt < 8; ++nt) acc[nt] = z4;

    for (int ch = 0; ch < 4; ++ch) {
        __syncthreads();
        for (int i = t; i < 2048; i += 256) {
            int r = i >> 4, c8 = (i & 15) << 3;
            *(uint4*)&wc[r][c8] = ((const uint4*)W1Tb)[ch * 2048 + i];
        }
        __syncthreads();

        f32x4 hacc[8];
#pragma unroll
        for (int nt = 0; nt < 8; ++nt) hacc[nt] = z4;
#pragma unroll
        for (int ks = 0; ks < 4; ++ks) {
            bf16x8 af = *(const bf16x8*)&xt[wrow + lr][ks * 32 + lg * 8];
#pragma unroll
            for (int nt = 0; nt < 8; ++nt) {
                bf16x8 bf = *(const bf16x8*)&wc[nt * 16 + lr][ks * 32 + lg * 8];
                hacc[nt] = __builtin_amdgcn_mfma_f32_16x16x32_bf16(af, bf, hacc[nt], 0, 0, 0);
            }
        }
#pragma unroll
        for (int nt = 0; nt < 8; ++nt) {
            float b1v = b1[ch * 128 + nt * 16 + lr];
#pragma unroll
            for (int rg = 0; rg < 4; ++rg) {
                float hval = fmaxf(hacc[nt][rg] + b1v, 0.f);
                ht[wrow + lg * 4 + rg][nt * 16 + lr] = f2b(hval);
            }
        }
        __syncthreads();

        for (int i = t; i < 2048; i += 256) {
            int r = i >> 4, c8i = i & 15;
            *(uint4*)&wc[r][c8i << 3] = ((const uint4*)W2Tb)[r * 64 + ch * 16 + c8i];
        }
        __syncthreads();

#pragma unroll
        for (int ks = 0; ks < 4; ++ks) {
            bf16x8 af = *(const bf16x8*)&ht[wrow + lr][ks * 32 + lg * 8];
#pragma unroll
            for (int nt = 0; nt < 8; ++nt) {
                bf16x8 bf = *(const bf16x8*)&wc[nt * 16 + lr][ks * 32 + lg * 8];
                acc[nt] = __builtin_amdgcn_mfma_f32_16x16x32_bf16(af, bf, acc[nt], 0, 0, 0);
            }
        }
    }

#pragma unroll
    for (int nt = 0; nt < 8; ++nt) {
        float b2v = b2[nt * 16 + lr];
        float s = 0.f, q = 0.f;
#pragma unroll
        for (int rg = 0; rg < 4; ++rg) {
            int r = row0 + wrow + lg * 4 + rg;
            float x1v = b2f(xt[wrow + lg * 4 + rg][nt * 16 + lr]);
            float z = x1v + acc[nt][rg] + b2v;
            if (r < NN) {
                out[(long)r * 128 + nt * 16 + lr] = z;
                s += z;
                q += z * z;
            }
        }
        s += __shfl_xor(s, 16); s += __shfl_xor(s, 32);
        q += __shfl_xor(q, 16); q += __shfl_xor(q, 32);
        if (lg == 0) { redS[wv][nt * 16 + lr] = s; redQ[wv][nt * 16 + lr] = q; }
    }
    __syncthreads();
    if (t < 128) {
        float S = redS[0][t] + redS[1][t] + redS[2][t] + redS[3][t];
        float Q = redQ[0][t] + redQ[1][t] + redQ[2][t] + redQ[3][t];
        atomicAdd(&stats2[t], S);
        atomicAdd(&stats2[128 + t], Q);
    }
}

// ---------------- launch ----------------

extern "C" void kernel_launch(void* const* d_in, const int* in_sizes, int n_in,
                              void* d_out, int out_size, void* d_ws, size_t ws_size,
                              hipStream_t stream) {
    const float* x     = (const float*)d_in[0];
    const int*   ei    = (const int*)d_in[1];
    const float* ew    = (const float*)d_in[2];
    const float* W     = (const float*)d_in[3];
    const float* b     = (const float*)d_in[4];
    const float* gamma = (const float*)d_in[5];
    const float* beta  = (const float*)d_in[6];
    const float* W1    = (const float*)d_in[7];
    const float* b1    = (const float*)d_in[8];
    const float* W2    = (const float*)d_in[9];
    const float* b2    = (const float*)d_in[10];
    float* out = (float*)d_out;
    float* ws  = (float*)d_ws;

    float* deg    = ws;                              // NN
    float* dinv   = ws + NN;                         // NN
    float* stats1 = ws + 2 * NN;                     // 256
    float* ac1    = stats1 + 256;                    // 256
    float* stats2 = ac1 + 256;                       // 256
    float* ac2    = stats2 + 256;                    // 256
    ushort* hb    = (ushort*)(ws + 2 * NN + 1024);   // NN*128 bf16
    ushort* WTb   = hb + (long)NN * 128;             // 16384
    ushort* W1Tb  = WTb + 16384;                     // 65536
    ushort* W2Tb  = W1Tb + 65536;                    // 65536
    float*  fend  = ws + 2 * NN + 1024 + (long)NN * 64 + 73728;
    int*   cnt    = (int*)fend;                      // NN
    int*   start  = cnt + NN;                        // NN+1
    int*   cursor = start + NN + 1;                  // NN
    uint2* csr    = (uint2*)(cursor + NN + 1);       // EE records (8B-aligned)
    float* y      = out;                             // x1 lives in d_out

    int nb = (NN + 63) / 64;   // 1563

    k_zero_stats<<<1, 256, 0, stream>>>(stats1, stats2);
    k_init<<<(NN + 255) / 256, 256, 0, stream>>>(deg, cnt);
    k_edge_deg<<<EE / 256, 256, 0, stream>>>(ei, ew, deg, cnt);
    k_dinv<<<(NN + 255) / 256, 256, 0, stream>>>(deg, dinv);
    k_scan<<<1, 256, 0, stream>>>(cnt, start, cursor);
    k_fill<<<EE / 256, 256, 0, stream>>>(ei, ew, dinv, cursor, csr);
    k_wcvt<<<576, 256, 0, stream>>>(W, W1, W2, WTb, W1Tb, W2Tb);
    k_xw<<<nb, 256, 0, stream>>>(x, WTb, hb);
    k_gather<<<(NN + 3) / 4, 256, 0, stream>>>(x, hb, dinv, b, start, csr, y);
    k_bn_stats<<<(NN + 255) / 256, 256, 0, stream>>>(y, stats1);
    k_bn_fin<<<1, 128, 0, stream>>>(stats1, gamma, beta, ac1);
    k_mlp<<<nb, 256, 0, stream>>>(y, ac1, W1Tb, b1, W2Tb, b2, out, stats2);
    k_bn_fin<<<1, 128, 0, stream>>>(stats2, gamma, beta, ac2);
    k_affine<<<(NN * 32) / 256, 256, 0, stream>>>(out, ac2);
}

// Round 5
// 565.784 us; speedup vs baseline: 3.1807x; 1.3889x over previous
//
#include <hip/hip_runtime.h>

#define NN 100000
#define EE 1600000
#define DD 128
#define FFD 512
#define EPSV 1e-5f

#define SCB 98   // scan blocks: ceil(100000/1024)

typedef __attribute__((ext_vector_type(8))) short bf16x8;
typedef __attribute__((ext_vector_type(4))) float f32x4;

__device__ __forceinline__ ushort f2b(float f) {          // fp32 -> bf16 RNE
    uint u = __float_as_uint(f);
    return (ushort)((u + 0x7FFF + ((u >> 16) & 1)) >> 16);
}
__device__ __forceinline__ float b2f(ushort u) {
    return __uint_as_float(((uint)u) << 16);
}

// ---------------- small utility kernels ----------------

__global__ __launch_bounds__(256) void k_zero_stats(float* s1, float* s2) {
    int t = threadIdx.x;
    s1[t] = 0.f;
    s2[t] = 0.f;
}

__global__ __launch_bounds__(256) void k_init(float* deg, int* cnt) {
    int i = blockIdx.x * 256 + threadIdx.x;
    if (i < NN) { deg[i] = 1.0f; cnt[i] = 0; }   // self-loop weight 1
}

__global__ __launch_bounds__(256) void k_edge_deg(const int* __restrict__ ei,
                                                  const float* __restrict__ ew,
                                                  float* __restrict__ deg,
                                                  int* __restrict__ cnt) {
    int e = blockIdx.x * 256 + threadIdx.x;
    if (e < EE) {
        int dst = ei[EE + e];
        atomicAdd(&deg[dst], ew[e]);
        atomicAdd(&cnt[dst], 1);
    }
}

__global__ __launch_bounds__(256) void k_dinv(const float* __restrict__ deg,
                                              float* __restrict__ dinv) {
    int i = blockIdx.x * 256 + threadIdx.x;
    if (i < NN) dinv[i] = rsqrtf(deg[i]);
}

// ---------------- hierarchical exclusive scan of cnt ----------------

__global__ __launch_bounds__(256) void k_scan_part(const int* __restrict__ cnt,
                                                   int* __restrict__ bsum) {
    __shared__ int red[4];
    int b = blockIdx.x, t = threadIdx.x;
    int base = b * 1024 + t * 4;
    int s = 0;
#pragma unroll
    for (int j = 0; j < 4; ++j) {
        int i = base + j;
        if (i < NN) s += cnt[i];
    }
#pragma unroll
    for (int d = 1; d < 64; d <<= 1) s += __shfl_xor(s, d);
    if ((t & 63) == 0) red[t >> 6] = s;
    __syncthreads();
    if (t == 0) bsum[b] = red[0] + red[1] + red[2] + red[3];
}

__global__ __launch_bounds__(128) void k_scan_base(int* __restrict__ bsum,
                                                   int* __restrict__ bbase,
                                                   int* __restrict__ start) {
    if (threadIdx.x == 0) {
        int run = 0;
        for (int i = 0; i < SCB; ++i) { bbase[i] = run; run += bsum[i]; }
        start[NN] = run;   // == EE
    }
}

__global__ __launch_bounds__(256) void k_scan_fin(const int* __restrict__ cnt,
                                                  const int* __restrict__ bbase,
                                                  int* __restrict__ start,
                                                  int* __restrict__ cursor) {
    __shared__ int ts[256];
    int b = blockIdx.x, t = threadIdx.x;
    int base = b * 1024 + t * 4;
    int v[4];
    int s = 0;
#pragma unroll
    for (int j = 0; j < 4; ++j) {
        int i = base + j;
        v[j] = (i < NN) ? cnt[i] : 0;
        s += v[j];
    }
    ts[t] = s;
    __syncthreads();
    // Hillis-Steele inclusive scan over 256 thread sums
    for (int d = 1; d < 256; d <<= 1) {
        int add = (t >= d) ? ts[t - d] : 0;
        __syncthreads();
        ts[t] += add;
        __syncthreads();
    }
    int run = bbase[b] + ts[t] - s;   // exclusive offset for this thread
#pragma unroll
    for (int j = 0; j < 4; ++j) {
        int i = base + j;
        if (i < NN) {
            start[i] = run;
            cursor[i] = run;
            run += v[j];
        }
    }
}

// ---------------- fill CSR records (src, norm) bucketed by dst ----------------

__global__ __launch_bounds__(256) void k_fill(const int* __restrict__ ei,
                                              const float* __restrict__ ew,
                                              const float* __restrict__ dinv,
                                              int* __restrict__ cursor,
                                              uint2* __restrict__ csr) {
    int e = blockIdx.x * 256 + threadIdx.x;
    if (e < EE) {
        int src = ei[e];
        int dst = ei[EE + e];
        float nrm = dinv[src] * ew[e] * dinv[dst];
        int pos = atomicAdd(&cursor[dst], 1);
        csr[pos] = make_uint2((uint)src, __float_as_uint(nrm));
    }
}

// ---------------- one-time weight transpose + bf16 convert ----------------

__global__ __launch_bounds__(256) void k_wcvt(const float* __restrict__ W,
                                              const float* __restrict__ W1,
                                              const float* __restrict__ W2,
                                              ushort* __restrict__ WTb,
                                              ushort* __restrict__ W1Tb,
                                              ushort* __restrict__ W2Tb) {
    int i = blockIdx.x * 256 + threadIdx.x;
    if (i < 16384) {
        int n = i >> 7, k = i & 127;
        WTb[i] = f2b(W[k * 128 + n]);
    } else if (i < 16384 + 65536) {
        int j = i - 16384;
        int f = j >> 7, k = j & 127;
        W1Tb[j] = f2b(W1[k * 512 + f]);
    } else {
        int j = i - 16384 - 65536;
        int jj = j >> 9, f = j & 511;
        W2Tb[j] = f2b(W2[f * 128 + jj]);
    }
}

// ---------------- h = x @ W via MFMA, h stored bf16 ----------------

__global__ __launch_bounds__(256) void k_xw(const float* __restrict__ x,
                                            const ushort* __restrict__ WTb,
                                            ushort* __restrict__ hb) {
    __shared__ __align__(16) ushort xt[64][136];
    __shared__ __align__(16) ushort wt[128][136];
    int t = threadIdx.x;
    int row0 = blockIdx.x * 64;

    for (int i = t; i < 2048; i += 256) {
        int r = i >> 4, c8 = (i & 15) << 3;
        *(uint4*)&wt[r][c8] = ((const uint4*)WTb)[i];
    }
    for (int i = t; i < 2048; i += 256) {
        int r = i >> 5, c4 = (i & 31) << 2;
        int gr = row0 + r;
        float4 v = make_float4(0.f, 0.f, 0.f, 0.f);
        if (gr < NN) v = ((const float4*)x)[(long)gr * 32 + (i & 31)];
        ushort4 o;
        o.x = f2b(v.x); o.y = f2b(v.y); o.z = f2b(v.z); o.w = f2b(v.w);
        *(ushort4*)&xt[r][c4] = o;
    }
    __syncthreads();

    int wv = t >> 6, l = t & 63;
    int lr = l & 15, lg = l >> 4;
    int wrow = wv * 16;

    f32x4 acc[8];
    f32x4 z4 = {0.f, 0.f, 0.f, 0.f};
#pragma unroll
    for (int nt = 0; nt < 8; ++nt) acc[nt] = z4;

#pragma unroll
    for (int ks = 0; ks < 4; ++ks) {
        bf16x8 af = *(const bf16x8*)&xt[wrow + lr][ks * 32 + lg * 8];
#pragma unroll
        for (int nt = 0; nt < 8; ++nt) {
            bf16x8 bf = *(const bf16x8*)&wt[nt * 16 + lr][ks * 32 + lg * 8];
            acc[nt] = __builtin_amdgcn_mfma_f32_16x16x32_bf16(af, bf, acc[nt], 0, 0, 0);
        }
    }

#pragma unroll
    for (int nt = 0; nt < 8; ++nt) {
#pragma unroll
        for (int rg = 0; rg < 4; ++rg) {
            int r = row0 + wrow + lg * 4 + rg;
            if (r < NN) hb[(long)r * 128 + nt * 16 + lr] = f2b(acc[nt][rg]);
        }
    }
}

// ---------------- gather: y[n] = x[n] + dinv[n]^2*h[n] + b + sum_e norm*h[src] ----------------

__global__ __launch_bounds__(256) void k_gather(const float* __restrict__ x,
                                                const ushort* __restrict__ hb,
                                                const float* __restrict__ dinv,
                                                const float* __restrict__ b,
                                                const int* __restrict__ start,
                                                const uint2* __restrict__ csr,
                                                float* __restrict__ y) {
    int t = threadIdx.x;
    int wv = t >> 6, l = t & 63;
    int node = blockIdx.x * 4 + wv;
    if (node >= NN) return;
    int s0 = start[node], s1 = start[node + 1];
    const uint* hbu = (const uint*)hb;
    float acc0 = 0.f, acc1 = 0.f;
    int i = s0;
    for (; i + 2 <= s1; i += 2) {
        uint2 r0 = csr[i], r1 = csr[i + 1];
        uint h0 = hbu[(long)(int)r0.x * 64 + l];
        uint h1 = hbu[(long)(int)r1.x * 64 + l];
        float n0 = __uint_as_float(r0.y), n1 = __uint_as_float(r1.y);
        acc0 = fmaf(n0, b2f((ushort)(h0 & 0xFFFF)), acc0);
        acc1 = fmaf(n0, b2f((ushort)(h0 >> 16)), acc1);
        acc0 = fmaf(n1, b2f((ushort)(h1 & 0xFFFF)), acc0);
        acc1 = fmaf(n1, b2f((ushort)(h1 >> 16)), acc1);
    }
    if (i < s1) {
        uint2 r0 = csr[i];
        uint h0 = hbu[(long)(int)r0.x * 64 + l];
        float n0 = __uint_as_float(r0.y);
        acc0 = fmaf(n0, b2f((ushort)(h0 & 0xFFFF)), acc0);
        acc1 = fmaf(n0, b2f((ushort)(h0 >> 16)), acc1);
    }
    float dv = dinv[node];
    float sl = dv * dv;
    uint hs = hbu[(long)node * 64 + l];
    float2 xv = ((const float2*)x)[(long)node * 64 + l];
    float2 bv = ((const float2*)b)[l];
    float o0 = xv.x + sl * b2f((ushort)(hs & 0xFFFF)) + bv.x + acc0;
    float o1 = xv.y + sl * b2f((ushort)(hs >> 16)) + bv.y + acc1;
    ((float2*)y)[(long)node * 64 + l] = make_float2(o0, o1);
}

// ---------------- BN stats ----------------

__global__ __launch_bounds__(256) void k_bn_stats(const float* __restrict__ v,
                                                  float* __restrict__ stats) {
    __shared__ float red[256];
    int t = threadIdx.x;
    int c = t & 127;
    int half = t >> 7;
    int r0 = blockIdx.x * 256 + half;
    float s = 0.f, q = 0.f;
    for (int j = 0; j < 128; ++j) {
        int r = r0 + 2 * j;
        if (r < NN) {
            float val = v[(long)r * DD + c];
            s += val;
            q += val * val;
        }
    }
    red[t] = s;
    __syncthreads();
    if (half == 0) atomicAdd(&stats[c], red[c] + red[c + 128]);
    __syncthreads();
    red[t] = q;
    __syncthreads();
    if (half == 0) atomicAdd(&stats[128 + c], red[c] + red[c + 128]);
}

__global__ __launch_bounds__(128) void k_bn_fin(const float* __restrict__ stats,
                                                const float* __restrict__ gamma,
                                                const float* __restrict__ beta,
                                                float* __restrict__ ac) {
    int c = threadIdx.x;
    float mu = stats[c] * (1.0f / NN);
    float var = stats[128 + c] * (1.0f / NN) - mu * mu;
    float a = gamma[c] * rsqrtf(var + EPSV);
    ac[c] = a;
    ac[128 + c] = beta[c] - mu * a;
}

__global__ __launch_bounds__(256) void k_affine(float* __restrict__ v,
                                                const float* __restrict__ ac) {
    long i = (long)blockIdx.x * 256 + threadIdx.x;   // float4 units
    int c4i = (int)(i & 31);
    float4 a = ((const float4*)ac)[c4i];
    float4 cc = ((const float4*)(ac + 128))[c4i];
    float4 v4 = ((float4*)v)[i];
    v4.x = a.x * v4.x + cc.x;
    v4.y = a.y * v4.y + cc.y;
    v4.z = a.z * v4.z + cc.z;
    v4.w = a.w * v4.w + cc.w;
    ((float4*)v)[i] = v4;
}

// ---------------- fused MLP via MFMA ----------------

__global__ __launch_bounds__(256) void k_mlp(const float* __restrict__ y,
                                             const float* __restrict__ ac1,
                                             const ushort* __restrict__ W1Tb,
                                             const float* __restrict__ b1,
                                             const ushort* __restrict__ W2Tb,
                                             const float* __restrict__ b2,
                                             float* __restrict__ out,
                                             float* __restrict__ stats2) {
    __shared__ __align__(16) ushort xt[64][136];
    __shared__ __align__(16) ushort ht[64][136];
    __shared__ __align__(16) ushort wc[128][136];
    __shared__ float redS[4][128];
    __shared__ float redQ[4][128];
    int t = threadIdx.x;
    int row0 = blockIdx.x * 64;

    for (int i = t; i < 2048; i += 256) {
        int r = i >> 5, c4i = i & 31;
        int gr = row0 + r;
        float4 v = make_float4(0.f, 0.f, 0.f, 0.f);
        if (gr < NN) v = ((const float4*)y)[(long)gr * 32 + c4i];
        float4 a = ((const float4*)ac1)[c4i];
        float4 cc = ((const float4*)(ac1 + 128))[c4i];
        ushort4 o;
        o.x = f2b(a.x * v.x + cc.x);
        o.y = f2b(a.y * v.y + cc.y);
        o.z = f2b(a.z * v.z + cc.z);
        o.w = f2b(a.w * v.w + cc.w);
        *(ushort4*)&xt[r][c4i << 2] = o;
    }

    int wv = t >> 6, l = t & 63;
    int lr = l & 15, lg = l >> 4;
    int wrow = wv * 16;

    f32x4 acc[8];
    f32x4 z4 = {0.f, 0.f, 0.f, 0.f};
#pragma unroll
    for (int nt = 0; nt < 8; ++nt) acc[nt] = z4;

    for (int ch = 0; ch < 4; ++ch) {
        __syncthreads();
        for (int i = t; i < 2048; i += 256) {
            int r = i >> 4, c8 = (i & 15) << 3;
            *(uint4*)&wc[r][c8] = ((const uint4*)W1Tb)[ch * 2048 + i];
        }
        __syncthreads();

        f32x4 hacc[8];
#pragma unroll
        for (int nt = 0; nt < 8; ++nt) hacc[nt] = z4;
#pragma unroll
        for (int ks = 0; ks < 4; ++ks) {
            bf16x8 af = *(const bf16x8*)&xt[wrow + lr][ks * 32 + lg * 8];
#pragma unroll
            for (int nt = 0; nt < 8; ++nt) {
                bf16x8 bf = *(const bf16x8*)&wc[nt * 16 + lr][ks * 32 + lg * 8];
                hacc[nt] = __builtin_amdgcn_mfma_f32_16x16x32_bf16(af, bf, hacc[nt], 0, 0, 0);
            }
        }
#pragma unroll
        for (int nt = 0; nt < 8; ++nt) {
            float b1v = b1[ch * 128 + nt * 16 + lr];
#pragma unroll
            for (int rg = 0; rg < 4; ++rg) {
                float hval = fmaxf(hacc[nt][rg] + b1v, 0.f);
                ht[wrow + lg * 4 + rg][nt * 16 + lr] = f2b(hval);
            }
        }
        __syncthreads();

        for (int i = t; i < 2048; i += 256) {
            int r = i >> 4, c8i = i & 15;
            *(uint4*)&wc[r][c8i << 3] = ((const uint4*)W2Tb)[r * 64 + ch * 16 + c8i];
        }
        __syncthreads();

#pragma unroll
        for (int ks = 0; ks < 4; ++ks) {
            bf16x8 af = *(const bf16x8*)&ht[wrow + lr][ks * 32 + lg * 8];
#pragma unroll
            for (int nt = 0; nt < 8; ++nt) {
                bf16x8 bf = *(const bf16x8*)&wc[nt * 16 + lr][ks * 32 + lg * 8];
                acc[nt] = __builtin_amdgcn_mfma_f32_16x16x32_bf16(af, bf, acc[nt], 0, 0, 0);
            }
        }
    }

#pragma unroll
    for (int nt = 0; nt < 8; ++nt) {
        float b2v = b2[nt * 16 + lr];
        float s = 0.f, q = 0.f;
#pragma unroll
        for (int rg = 0; rg < 4; ++rg) {
            int r = row0 + wrow + lg * 4 + rg;
            float x1v = b2f(xt[wrow + lg * 4 + rg][nt * 16 + lr]);
            float z = x1v + acc[nt][rg] + b2v;
            if (r < NN) {
                out[(long)r * 128 + nt * 16 + lr] = z;
                s += z;
                q += z * z;
            }
        }
        s += __shfl_xor(s, 16); s += __shfl_xor(s, 32);
        q += __shfl_xor(q, 16); q += __shfl_xor(q, 32);
        if (lg == 0) { redS[wv][nt * 16 + lr] = s; redQ[wv][nt * 16 + lr] = q; }
    }
    __syncthreads();
    if (t < 128) {
        float S = redS[0][t] + redS[1][t] + redS[2][t] + redS[3][t];
        float Q = redQ[0][t] + redQ[1][t] + redQ[2][t] + redQ[3][t];
        atomicAdd(&stats2[t], S);
        atomicAdd(&stats2[128 + t], Q);
    }
}

// ---------------- launch ----------------

extern "C" void kernel_launch(void* const* d_in, const int* in_sizes, int n_in,
                              void* d_out, int out_size, void* d_ws, size_t ws_size,
                              hipStream_t stream) {
    const float* x     = (const float*)d_in[0];
    const int*   ei    = (const int*)d_in[1];
    const float* ew    = (const float*)d_in[2];
    const float* W     = (const float*)d_in[3];
    const float* b     = (const float*)d_in[4];
    const float* gamma = (const float*)d_in[5];
    const float* beta  = (const float*)d_in[6];
    const float* W1    = (const float*)d_in[7];
    const float* b1    = (const float*)d_in[8];
    const float* W2    = (const float*)d_in[9];
    const float* b2    = (const float*)d_in[10];
    float* out = (float*)d_out;
    float* ws  = (float*)d_ws;

    float* deg    = ws;                              // NN
    float* dinv   = ws + NN;                         // NN
    float* stats1 = ws + 2 * NN;                     // 256
    float* ac1    = stats1 + 256;                    // 256
    float* stats2 = ac1 + 256;                       // 256
    float* ac2    = stats2 + 256;                    // 256
    ushort* hb    = (ushort*)(ws + 2 * NN + 1024);   // NN*128 bf16
    ushort* WTb   = hb + (long)NN * 128;             // 16384
    ushort* W1Tb  = WTb + 16384;                     // 65536
    ushort* W2Tb  = W1Tb + 65536;                    // 65536
    float*  fend  = ws + 2 * NN + 1024 + (long)NN * 64 + 73728;
    int*   cnt    = (int*)fend;                      // NN
    int*   start  = cnt + NN;                        // NN+1
    int*   cursor = start + NN + 1;                  // NN
    int*   bsum   = cursor + NN;                     // SCB
    int*   bbase  = bsum + SCB;                      // SCB
    uint2* csr    = (uint2*)(((uintptr_t)(bbase + SCB) + 7) & ~(uintptr_t)7);  // EE records
    float* y      = out;                             // x1 lives in d_out

    int nb = (NN + 63) / 64;   // 1563

    k_zero_stats<<<1, 256, 0, stream>>>(stats1, stats2);
    k_init<<<(NN + 255) / 256, 256, 0, stream>>>(deg, cnt);
    k_edge_deg<<<EE / 256, 256, 0, stream>>>(ei, ew, deg, cnt);
    k_dinv<<<(NN + 255) / 256, 256, 0, stream>>>(deg, dinv);
    k_scan_part<<<SCB, 256, 0, stream>>>(cnt, bsum);
    k_scan_base<<<1, 128, 0, stream>>>(bsum, bbase, start);
    k_scan_fin<<<SCB, 256, 0, stream>>>(cnt, bbase, start, cursor);
    k_fill<<<EE / 256, 256, 0, stream>>>(ei, ew, dinv, cursor, csr);
    k_wcvt<<<576, 256, 0, stream>>>(W, W1, W2, WTb, W1Tb, W2Tb);
    k_xw<<<nb, 256, 0, stream>>>(x, WTb, hb);
    k_gather<<<(NN + 3) / 4, 256, 0, stream>>>(x, hb, dinv, b, start, csr, y);
    k_bn_stats<<<(NN + 255) / 256, 256, 0, stream>>>(y, stats1);
    k_bn_fin<<<1, 128, 0, stream>>>(stats1, gamma, beta, ac1);
    k_mlp<<<nb, 256, 0, stream>>>(y, ac1, W1Tb, b1, W2Tb, b2, out, stats2);
    k_bn_fin<<<1, 128, 0, stream>>>(stats2, gamma, beta, ac2);
    k_affine<<<(NN * 32) / 256, 256, 0, stream>>>(out, ac2);
}

// Round 6
// 561.419 us; speedup vs baseline: 3.2054x; 1.0078x over previous
//
#include <hip/hip_runtime.h>

#define NN 100000
#define EE 1600000
#define DD 128
#define FFD 512
#define EPSV 1e-5f

#define SCB 98   // scan blocks: ceil(100000/1024)

typedef __attribute__((ext_vector_type(8))) short bf16x8;
typedef __attribute__((ext_vector_type(4))) float f32x4;

__device__ __forceinline__ ushort f2b(float f) {          // fp32 -> bf16 RNE
    uint u = __float_as_uint(f);
    return (ushort)((u + 0x7FFF + ((u >> 16) & 1)) >> 16);
}
__device__ __forceinline__ float b2f(ushort u) {
    return __uint_as_float(((uint)u) << 16);
}

// ---------------- small utility kernels ----------------

__global__ __launch_bounds__(256) void k_zero_stats(float* s1, float* s2) {
    int t = threadIdx.x;
    s1[t] = 0.f;
    s2[t] = 0.f;
}

__global__ __launch_bounds__(256) void k_init(float* deg, int* cnt) {
    int i = blockIdx.x * 256 + threadIdx.x;
    if (i < NN) { deg[i] = 1.0f; cnt[i] = 0; }   // self-loop weight 1
}

__global__ __launch_bounds__(256) void k_edge_deg(const int* __restrict__ ei,
                                                  const float* __restrict__ ew,
                                                  float* __restrict__ deg,
                                                  int* __restrict__ cnt) {
    int e = blockIdx.x * 256 + threadIdx.x;
    if (e < EE) {
        int dst = ei[EE + e];
        atomicAdd(&deg[dst], ew[e]);
        atomicAdd(&cnt[dst], 1);
    }
}

__global__ __launch_bounds__(256) void k_dinv(const float* __restrict__ deg,
                                              float* __restrict__ dinv) {
    int i = blockIdx.x * 256 + threadIdx.x;
    if (i < NN) dinv[i] = rsqrtf(deg[i]);
}

// ---------------- hierarchical exclusive scan of cnt ----------------

__global__ __launch_bounds__(256) void k_scan_part(const int* __restrict__ cnt,
                                                   int* __restrict__ bsum) {
    __shared__ int red[4];
    int b = blockIdx.x, t = threadIdx.x;
    int base = b * 1024 + t * 4;
    int s = 0;
#pragma unroll
    for (int j = 0; j < 4; ++j) {
        int i = base + j;
        if (i < NN) s += cnt[i];
    }
#pragma unroll
    for (int d = 1; d < 64; d <<= 1) s += __shfl_xor(s, d);
    if ((t & 63) == 0) red[t >> 6] = s;
    __syncthreads();
    if (t == 0) bsum[b] = red[0] + red[1] + red[2] + red[3];
}

__global__ __launch_bounds__(128) void k_scan_base(int* __restrict__ bsum,
                                                   int* __restrict__ bbase,
                                                   int* __restrict__ start) {
    if (threadIdx.x == 0) {
        int run = 0;
        for (int i = 0; i < SCB; ++i) { bbase[i] = run; run += bsum[i]; }
        start[NN] = run;   // == EE
    }
}

__global__ __launch_bounds__(256) void k_scan_fin(const int* __restrict__ cnt,
                                                  const int* __restrict__ bbase,
                                                  int* __restrict__ start,
                                                  int* __restrict__ cursor) {
    __shared__ int ts[256];
    int b = blockIdx.x, t = threadIdx.x;
    int base = b * 1024 + t * 4;
    int v[4];
    int s = 0;
#pragma unroll
    for (int j = 0; j < 4; ++j) {
        int i = base + j;
        v[j] = (i < NN) ? cnt[i] : 0;
        s += v[j];
    }
    ts[t] = s;
    __syncthreads();
    for (int d = 1; d < 256; d <<= 1) {
        int add = (t >= d) ? ts[t - d] : 0;
        __syncthreads();
        ts[t] += add;
        __syncthreads();
    }
    int run = bbase[b] + ts[t] - s;   // exclusive offset for this thread
#pragma unroll
    for (int j = 0; j < 4; ++j) {
        int i = base + j;
        if (i < NN) {
            start[i] = run;
            cursor[i] = run;
            run += v[j];
        }
    }
}

// ---------------- fill CSR records (src, norm) bucketed by dst ----------------

__global__ __launch_bounds__(256) void k_fill(const int* __restrict__ ei,
                                              const float* __restrict__ ew,
                                              const float* __restrict__ dinv,
                                              int* __restrict__ cursor,
                                              uint2* __restrict__ csr) {
    int e = blockIdx.x * 256 + threadIdx.x;
    if (e < EE) {
        int src = ei[e];
        int dst = ei[EE + e];
        float nrm = dinv[src] * ew[e] * dinv[dst];
        int pos = atomicAdd(&cursor[dst], 1);
        csr[pos] = make_uint2((uint)src, __float_as_uint(nrm));
    }
}

// ---------------- one-time weight transpose + bf16 convert ----------------

__global__ __launch_bounds__(256) void k_wcvt(const float* __restrict__ W,
                                              const float* __restrict__ W1,
                                              const float* __restrict__ W2,
                                              ushort* __restrict__ WTb,
                                              ushort* __restrict__ W1Tb,
                                              ushort* __restrict__ W2Tb) {
    int i = blockIdx.x * 256 + threadIdx.x;
    if (i < 16384) {
        int n = i >> 7, k = i & 127;
        WTb[i] = f2b(W[k * 128 + n]);
    } else if (i < 16384 + 65536) {
        int j = i - 16384;
        int f = j >> 7, k = j & 127;
        W1Tb[j] = f2b(W1[k * 512 + f]);
    } else {
        int j = i - 16384 - 65536;
        int jj = j >> 9, f = j & 511;
        W2Tb[j] = f2b(W2[f * 128 + jj]);
    }
}

// ---------------- h = x @ W via MFMA, h stored bf16 ----------------

__global__ __launch_bounds__(256) void k_xw(const float* __restrict__ x,
                                            const ushort* __restrict__ WTb,
                                            ushort* __restrict__ hb) {
    __shared__ __align__(16) ushort xt[64][136];
    __shared__ __align__(16) ushort wt[128][136];
    int t = threadIdx.x;
    int row0 = blockIdx.x * 64;

    for (int i = t; i < 2048; i += 256) {
        int r = i >> 4, c8 = (i & 15) << 3;
        *(uint4*)&wt[r][c8] = ((const uint4*)WTb)[i];
    }
    for (int i = t; i < 2048; i += 256) {
        int r = i >> 5, c4 = (i & 31) << 2;
        int gr = row0 + r;
        float4 v = make_float4(0.f, 0.f, 0.f, 0.f);
        if (gr < NN) v = ((const float4*)x)[(long)gr * 32 + (i & 31)];
        ushort4 o;
        o.x = f2b(v.x); o.y = f2b(v.y); o.z = f2b(v.z); o.w = f2b(v.w);
        *(ushort4*)&xt[r][c4] = o;
    }
    __syncthreads();

    int wv = t >> 6, l = t & 63;
    int lr = l & 15, lg = l >> 4;
    int wrow = wv * 16;

    f32x4 acc[8];
    f32x4 z4 = {0.f, 0.f, 0.f, 0.f};
#pragma unroll
    for (int nt = 0; nt < 8; ++nt) acc[nt] = z4;

#pragma unroll
    for (int ks = 0; ks < 4; ++ks) {
        bf16x8 af = *(const bf16x8*)&xt[wrow + lr][ks * 32 + lg * 8];
#pragma unroll
        for (int nt = 0; nt < 8; ++nt) {
            bf16x8 bf = *(const bf16x8*)&wt[nt * 16 + lr][ks * 32 + lg * 8];
            acc[nt] = __builtin_amdgcn_mfma_f32_16x16x32_bf16(af, bf, acc[nt], 0, 0, 0);
        }
    }

#pragma unroll
    for (int nt = 0; nt < 8; ++nt) {
#pragma unroll
        for (int rg = 0; rg < 4; ++rg) {
            int r = row0 + wrow + lg * 4 + rg;
            if (r < NN) hb[(long)r * 128 + nt * 16 + lr] = f2b(acc[nt][rg]);
        }
    }
}

// ---------------- gather + BN1 stats ----------------
// 32 nodes per block, 8 sequential nodes per wave, lane = 2 features.

__global__ __launch_bounds__(256) void k_gather(const float* __restrict__ x,
                                                const ushort* __restrict__ hb,
                                                const float* __restrict__ dinv,
                                                const float* __restrict__ b,
                                                const int* __restrict__ start,
                                                const uint2* __restrict__ csr,
                                                float* __restrict__ y,
                                                float* __restrict__ stats1) {
    __shared__ float sred[4][128];
    __shared__ float qred[4][128];
    int t = threadIdx.x;
    int wv = t >> 6, l = t & 63;
    const uint* hbu = (const uint*)hb;
    float2 bv = ((const float2*)b)[l];
    float s0 = 0.f, s1 = 0.f, q0 = 0.f, q1 = 0.f;

    for (int k = 0; k < 8; ++k) {
        int node = blockIdx.x * 32 + wv * 8 + k;   // grid=3125 -> always < NN
        int e0 = start[node], e1 = start[node + 1];
        float a0 = 0.f, a1 = 0.f;
        int i = e0;
        for (; i + 2 <= e1; i += 2) {
            uint2 r0 = csr[i], r1 = csr[i + 1];
            uint h0 = hbu[(long)(int)r0.x * 64 + l];
            uint h1 = hbu[(long)(int)r1.x * 64 + l];
            float n0 = __uint_as_float(r0.y), n1 = __uint_as_float(r1.y);
            a0 = fmaf(n0, b2f((ushort)(h0 & 0xFFFF)), a0);
            a1 = fmaf(n0, b2f((ushort)(h0 >> 16)), a1);
            a0 = fmaf(n1, b2f((ushort)(h1 & 0xFFFF)), a0);
            a1 = fmaf(n1, b2f((ushort)(h1 >> 16)), a1);
        }
        if (i < e1) {
            uint2 r0 = csr[i];
            uint h0 = hbu[(long)(int)r0.x * 64 + l];
            float n0 = __uint_as_float(r0.y);
            a0 = fmaf(n0, b2f((ushort)(h0 & 0xFFFF)), a0);
            a1 = fmaf(n0, b2f((ushort)(h0 >> 16)), a1);
        }
        float dv = dinv[node];
        float sl = dv * dv;
        uint hs = hbu[(long)node * 64 + l];
        float2 xv = ((const float2*)x)[(long)node * 64 + l];
        float o0 = xv.x + sl * b2f((ushort)(hs & 0xFFFF)) + bv.x + a0;
        float o1 = xv.y + sl * b2f((ushort)(hs >> 16)) + bv.y + a1;
        ((float2*)y)[(long)node * 64 + l] = make_float2(o0, o1);
        s0 += o0; s1 += o1;
        q0 += o0 * o0; q1 += o1 * o1;
    }
    sred[wv][2 * l] = s0; sred[wv][2 * l + 1] = s1;
    qred[wv][2 * l] = q0; qred[wv][2 * l + 1] = q1;
    __syncthreads();
    if (t < 128) {
        atomicAdd(&stats1[t], sred[0][t] + sred[1][t] + sred[2][t] + sred[3][t]);
        atomicAdd(&stats1[128 + t], qred[0][t] + qred[1][t] + qred[2][t] + qred[3][t]);
    }
}

// ---------------- BN finalize + affine ----------------

__global__ __launch_bounds__(128) void k_bn_fin(const float* __restrict__ stats,
                                                const float* __restrict__ gamma,
                                                const float* __restrict__ beta,
                                                float* __restrict__ ac) {
    int c = threadIdx.x;
    float mu = stats[c] * (1.0f / NN);
    float var = stats[128 + c] * (1.0f / NN) - mu * mu;
    float a = gamma[c] * rsqrtf(var + EPSV);
    ac[c] = a;
    ac[128 + c] = beta[c] - mu * a;
}

__global__ __launch_bounds__(256) void k_affine(float* __restrict__ v,
                                                const float* __restrict__ ac) {
    long i = (long)blockIdx.x * 256 + threadIdx.x;   // float4 units
    int c4i = (int)(i & 31);
    float4 a = ((const float4*)ac)[c4i];
    float4 cc = ((const float4*)(ac + 128))[c4i];
    float4 v4 = ((float4*)v)[i];
    v4.x = a.x * v4.x + cc.x;
    v4.y = a.y * v4.y + cc.y;
    v4.z = a.z * v4.z + cc.z;
    v4.w = a.w * v4.w + cc.w;
    ((float4*)v)[i] = v4;
}

// ---------------- fused MLP via MFMA (v2: 2x blocking + swapped GEMM2) ----------------
// Wave tile: 32 rows (rw half) x 64 cols (jw half).
// GEMM1: h = mfma(x-rows, W1T-rows): D col = f (=lane&15), row = r (=lg*4+reg).
// GEMM2 swapped: z^T = mfma(W2T-rows, ht-rows): D col = r, row = j.

__global__ __launch_bounds__(256) void k_mlp(const float* __restrict__ y,
                                             const float* __restrict__ ac1,
                                             const ushort* __restrict__ W1Tb,
                                             const float* __restrict__ b1,
                                             const ushort* __restrict__ W2Tb,
                                             const float* __restrict__ b2,
                                             float* __restrict__ out,
                                             float* __restrict__ stats2) {
    __shared__ __align__(16) ushort xt[64][136];
    __shared__ __align__(16) ushort ht[64][136];
    __shared__ __align__(16) ushort wc[128][136];
    int t = threadIdx.x;
    int row0 = blockIdx.x * 64;

    // stage x1 = affine(y) -> bf16
    for (int i = t; i < 2048; i += 256) {
        int r = i >> 5, c4i = i & 31;
        int gr = row0 + r;
        float4 v = make_float4(0.f, 0.f, 0.f, 0.f);
        if (gr < NN) v = ((const float4*)y)[(long)gr * 32 + c4i];
        float4 a = ((const float4*)ac1)[c4i];
        float4 cc = ((const float4*)(ac1 + 128))[c4i];
        ushort4 o;
        o.x = f2b(a.x * v.x + cc.x);
        o.y = f2b(a.y * v.y + cc.y);
        o.z = f2b(a.z * v.z + cc.z);
        o.w = f2b(a.w * v.w + cc.w);
        *(ushort4*)&xt[r][c4i << 2] = o;
    }

    int wv = t >> 6, l = t & 63;
    int lr = l & 15, lg = l >> 4;
    int rw = wv & 1;    // 32-row half
    int jw = wv >> 1;   // 64-col half

    f32x4 z4 = {0.f, 0.f, 0.f, 0.f};
    f32x4 acc[4][2];    // [jt][rt]
#pragma unroll
    for (int jt = 0; jt < 4; ++jt)
#pragma unroll
        for (int rt = 0; rt < 2; ++rt) acc[jt][rt] = z4;

    for (int ch = 0; ch < 4; ++ch) {
        __syncthreads();   // wc reuse (and xt staging at ch=0)
        for (int i = t; i < 2048; i += 256) {
            int r = i >> 4, c8 = (i & 15) << 3;
            *(uint4*)&wc[r][c8] = ((const uint4*)W1Tb)[ch * 2048 + i];
        }
        __syncthreads();

        // GEMM1: hidden(32r x 64f) = relu(x1 @ W1c + b1c)
        f32x4 hacc[4][2];  // [ft][rt]
#pragma unroll
        for (int ft = 0; ft < 4; ++ft)
#pragma unroll
            for (int rt = 0; rt < 2; ++rt) hacc[ft][rt] = z4;
#pragma unroll
        for (int ks = 0; ks < 4; ++ks) {
            bf16x8 aR0 = *(const bf16x8*)&xt[rw * 32 + lr][ks * 32 + lg * 8];
            bf16x8 aR1 = *(const bf16x8*)&xt[rw * 32 + 16 + lr][ks * 32 + lg * 8];
#pragma unroll
            for (int ft = 0; ft < 4; ++ft) {
                bf16x8 bW = *(const bf16x8*)&wc[jw * 64 + ft * 16 + lr][ks * 32 + lg * 8];
                hacc[ft][0] = __builtin_amdgcn_mfma_f32_16x16x32_bf16(aR0, bW, hacc[ft][0], 0, 0, 0);
                hacc[ft][1] = __builtin_amdgcn_mfma_f32_16x16x32_bf16(aR1, bW, hacc[ft][1], 0, 0, 0);
            }
        }
#pragma unroll
        for (int ft = 0; ft < 4; ++ft) {
            float b1v = b1[ch * 128 + jw * 64 + ft * 16 + lr];
#pragma unroll
            for (int rt = 0; rt < 2; ++rt)
#pragma unroll
                for (int rg = 0; rg < 4; ++rg)
                    ht[rw * 32 + rt * 16 + lg * 4 + rg][jw * 64 + ft * 16 + lr] =
                        f2b(fmaxf(hacc[ft][rt][rg] + b1v, 0.f));
        }
        __syncthreads();   // all ht written, wc free

        for (int i = t; i < 2048; i += 256) {
            int r = i >> 4, c8i = i & 15;
            *(uint4*)&wc[r][c8i << 3] = ((const uint4*)W2Tb)[r * 64 + ch * 16 + c8i];
        }
        __syncthreads();

        // GEMM2 swapped: acc(j x r) += W2c-rows x ht-rows
#pragma unroll
        for (int ks = 0; ks < 4; ++ks) {
            bf16x8 qR0 = *(const bf16x8*)&ht[rw * 32 + lr][ks * 32 + lg * 8];
            bf16x8 qR1 = *(const bf16x8*)&ht[rw * 32 + 16 + lr][ks * 32 + lg * 8];
#pragma unroll
            for (int jt = 0; jt < 4; ++jt) {
                bf16x8 pW = *(const bf16x8*)&wc[jw * 64 + jt * 16 + lr][ks * 32 + lg * 8];
                acc[jt][0] = __builtin_amdgcn_mfma_f32_16x16x32_bf16(pW, qR0, acc[jt][0], 0, 0, 0);
                acc[jt][1] = __builtin_amdgcn_mfma_f32_16x16x32_bf16(pW, qR1, acc[jt][1], 0, 0, 0);
            }
        }
    }

    // epilogue: z = x1 + x2 + b2 (float4 stores), BN2 partials
    float sj[4][4], qj[4][4];
#pragma unroll
    for (int jt = 0; jt < 4; ++jt)
#pragma unroll
        for (int g = 0; g < 4; ++g) { sj[jt][g] = 0.f; qj[jt][g] = 0.f; }

#pragma unroll
    for (int jt = 0; jt < 4; ++jt) {
        int jb = jw * 64 + jt * 16 + lg * 4;
        float4 b2v = *(const float4*)&b2[jb];
#pragma unroll
        for (int rt = 0; rt < 2; ++rt) {
            int rloc = rw * 32 + rt * 16 + lr;
            int r = row0 + rloc;
            ushort4 xv = *(const ushort4*)&xt[rloc][jb];
            float z0 = b2f(xv.x) + acc[jt][rt][0] + b2v.x;
            float z1 = b2f(xv.y) + acc[jt][rt][1] + b2v.y;
            float z2 = b2f(xv.z) + acc[jt][rt][2] + b2v.z;
            float z3 = b2f(xv.w) + acc[jt][rt][3] + b2v.w;
            if (r < NN) {
                *(float4*)&out[(long)r * 128 + jb] = make_float4(z0, z1, z2, z3);
                sj[jt][0] += z0; sj[jt][1] += z1; sj[jt][2] += z2; sj[jt][3] += z3;
                qj[jt][0] += z0 * z0; qj[jt][1] += z1 * z1; qj[jt][2] += z2 * z2; qj[jt][3] += z3 * z3;
            }
        }
    }
    // reduce over the 16-lane r dimension (bits 1,2,4,8 of lane id)
#pragma unroll
    for (int jt = 0; jt < 4; ++jt)
#pragma unroll
        for (int g = 0; g < 4; ++g) {
#pragma unroll
            for (int d = 1; d < 16; d <<= 1) {
                sj[jt][g] += __shfl_xor(sj[jt][g], d);
                qj[jt][g] += __shfl_xor(qj[jt][g], d);
            }
        }
    __syncthreads();   // ht reads done; reuse as reduction buffer
    float* redS = (float*)&ht[0][0];    // [4][128]
    float* redQ = redS + 512;           // [4][128]
    if (lr == 0) {
#pragma unroll
        for (int jt = 0; jt < 4; ++jt)
#pragma unroll
            for (int g = 0; g < 4; ++g) {
                int j = jw * 64 + jt * 16 + lg * 4 + g;
                redS[wv * 128 + j] = sj[jt][g];
                redQ[wv * 128 + j] = qj[jt][g];
            }
    }
    __syncthreads();
    if (t < 128) {
        int w0 = (t >> 6) * 2;   // the two waves owning this j-half
        atomicAdd(&stats2[t], redS[w0 * 128 + t] + redS[(w0 + 1) * 128 + t]);
        atomicAdd(&stats2[128 + t], redQ[w0 * 128 + t] + redQ[(w0 + 1) * 128 + t]);
    }
}

// ---------------- launch ----------------

extern "C" void kernel_launch(void* const* d_in, const int* in_sizes, int n_in,
                              void* d_out, int out_size, void* d_ws, size_t ws_size,
                              hipStream_t stream) {
    const float* x     = (const float*)d_in[0];
    const int*   ei    = (const int*)d_in[1];
    const float* ew    = (const float*)d_in[2];
    const float* W     = (const float*)d_in[3];
    const float* b     = (const float*)d_in[4];
    const float* gamma = (const float*)d_in[5];
    const float* beta  = (const float*)d_in[6];
    const float* W1    = (const float*)d_in[7];
    const float* b1    = (const float*)d_in[8];
    const float* W2    = (const float*)d_in[9];
    const float* b2    = (const float*)d_in[10];
    float* out = (float*)d_out;
    float* ws  = (float*)d_ws;

    float* deg    = ws;                              // NN
    float* dinv   = ws + NN;                         // NN
    float* stats1 = ws + 2 * NN;                     // 256
    float* ac1    = stats1 + 256;                    // 256
    float* stats2 = ac1 + 256;                       // 256
    float* ac2    = stats2 + 256;                    // 256
    ushort* hb    = (ushort*)(ws + 2 * NN + 1024);   // NN*128 bf16
    ushort* WTb   = hb + (long)NN * 128;             // 16384
    ushort* W1Tb  = WTb + 16384;                     // 65536
    ushort* W2Tb  = W1Tb + 65536;                    // 65536
    float*  fend  = ws + 2 * NN + 1024 + (long)NN * 64 + 73728;
    int*   cnt    = (int*)fend;                      // NN
    int*   start  = cnt + NN;                        // NN+1
    int*   cursor = start + NN + 1;                  // NN
    int*   bsum   = cursor + NN;                     // SCB
    int*   bbase  = bsum + SCB;                      // SCB
    uint2* csr    = (uint2*)(((uintptr_t)(bbase + SCB) + 7) & ~(uintptr_t)7);  // EE records
    float* y      = out;                             // x1 lives in d_out

    int nb = (NN + 63) / 64;   // 1563

    k_zero_stats<<<1, 256, 0, stream>>>(stats1, stats2);
    k_init<<<(NN + 255) / 256, 256, 0, stream>>>(deg, cnt);
    k_edge_deg<<<EE / 256, 256, 0, stream>>>(ei, ew, deg, cnt);
    k_dinv<<<(NN + 255) / 256, 256, 0, stream>>>(deg, dinv);
    k_scan_part<<<SCB, 256, 0, stream>>>(cnt, bsum);
    k_scan_base<<<1, 128, 0, stream>>>(bsum, bbase, start);
    k_scan_fin<<<SCB, 256, 0, stream>>>(cnt, bbase, start, cursor);
    k_fill<<<EE / 256, 256, 0, stream>>>(ei, ew, dinv, cursor, csr);
    k_wcvt<<<576, 256, 0, stream>>>(W, W1, W2, WTb, W1Tb, W2Tb);
    k_xw<<<nb, 256, 0, stream>>>(x, WTb, hb);
    k_gather<<<NN / 32, 256, 0, stream>>>(x, hb, dinv, b, start, csr, y, stats1);
    k_bn_fin<<<1, 128, 0, stream>>>(stats1, gamma, beta, ac1);
    k_mlp<<<nb, 256, 0, stream>>>(y, ac1, W1Tb, b1, W2Tb, b2, out, stats2);
    k_bn_fin<<<1, 128, 0, stream>>>(stats2, gamma, beta, ac2);
    k_affine<<<(NN * 32) / 256, 256, 0, stream>>>(out, ac2);
}

// Round 7
// 530.806 us; speedup vs baseline: 3.3903x; 1.0577x over previous
//
#include <hip/hip_runtime.h>

#define NN 100000
#define EE 1600000
#define DD 128
#define FFD 512
#define EPSV 1e-5f

#define SCB 98   // scan blocks: ceil(100000/1024)

typedef __attribute__((ext_vector_type(8))) short bf16x8;
typedef __attribute__((ext_vector_type(4))) float f32x4;

__device__ __forceinline__ ushort f2b(float f) {          // fp32 -> bf16 RNE
    uint u = __float_as_uint(f);
    return (ushort)((u + 0x7FFF + ((u >> 16) & 1)) >> 16);
}
__device__ __forceinline__ float b2f(ushort u) {
    return __uint_as_float(((uint)u) << 16);
}

// ---------------- init: deg=1, cnt=0, stats=0 ----------------

__global__ __launch_bounds__(256) void k_init(float* deg, int* cnt,
                                              float* s1, float* s2) {
    int i = blockIdx.x * 256 + threadIdx.x;
    if (i < NN) { deg[i] = 1.0f; cnt[i] = 0; }   // self-loop weight 1
    if (blockIdx.x == 0) { s1[threadIdx.x] = 0.f; s2[threadIdx.x] = 0.f; }
}

__global__ __launch_bounds__(256) void k_edge_deg(const int* __restrict__ ei,
                                                  const float* __restrict__ ew,
                                                  float* __restrict__ deg,
                                                  int* __restrict__ cnt) {
    int e = blockIdx.x * 256 + threadIdx.x;
    if (e < EE) {
        int dst = ei[EE + e];
        atomicAdd(&deg[dst], ew[e]);
        atomicAdd(&cnt[dst], 1);
    }
}

__global__ __launch_bounds__(256) void k_dinv(const float* __restrict__ deg,
                                              float* __restrict__ dinv) {
    int i = blockIdx.x * 256 + threadIdx.x;
    if (i < NN) dinv[i] = rsqrtf(deg[i]);
}

// ---------------- hierarchical exclusive scan of cnt ----------------

__global__ __launch_bounds__(256) void k_scan_part(const int* __restrict__ cnt,
                                                   int* __restrict__ bsum) {
    __shared__ int red[4];
    int b = blockIdx.x, t = threadIdx.x;
    int base = b * 1024 + t * 4;
    int s = 0;
#pragma unroll
    for (int j = 0; j < 4; ++j) {
        int i = base + j;
        if (i < NN) s += cnt[i];
    }
#pragma unroll
    for (int d = 1; d < 64; d <<= 1) s += __shfl_xor(s, d);
    if ((t & 63) == 0) red[t >> 6] = s;
    __syncthreads();
    if (t == 0) bsum[b] = red[0] + red[1] + red[2] + red[3];
}

__global__ __launch_bounds__(128) void k_scan_base(int* __restrict__ bsum,
                                                   int* __restrict__ bbase,
                                                   int* __restrict__ start) {
    if (threadIdx.x == 0) {
        int run = 0;
        for (int i = 0; i < SCB; ++i) { bbase[i] = run; run += bsum[i]; }
        start[NN] = run;   // == EE
    }
}

__global__ __launch_bounds__(256) void k_scan_fin(const int* __restrict__ cnt,
                                                  const int* __restrict__ bbase,
                                                  int* __restrict__ start,
                                                  int* __restrict__ cursor) {
    __shared__ int ts[256];
    int b = blockIdx.x, t = threadIdx.x;
    int base = b * 1024 + t * 4;
    int v[4];
    int s = 0;
#pragma unroll
    for (int j = 0; j < 4; ++j) {
        int i = base + j;
        v[j] = (i < NN) ? cnt[i] : 0;
        s += v[j];
    }
    ts[t] = s;
    __syncthreads();
    for (int d = 1; d < 256; d <<= 1) {
        int add = (t >= d) ? ts[t - d] : 0;
        __syncthreads();
        ts[t] += add;
        __syncthreads();
    }
    int run = bbase[b] + ts[t] - s;   // exclusive offset for this thread
#pragma unroll
    for (int j = 0; j < 4; ++j) {
        int i = base + j;
        if (i < NN) {
            start[i] = run;
            cursor[i] = run;
            run += v[j];
        }
    }
}

// ---------------- fill CSR records (src, norm) bucketed by dst ----------------

__global__ __launch_bounds__(256) void k_fill(const int* __restrict__ ei,
                                              const float* __restrict__ ew,
                                              const float* __restrict__ dinv,
                                              int* __restrict__ cursor,
                                              uint2* __restrict__ csr) {
    int e = blockIdx.x * 256 + threadIdx.x;
    if (e < EE) {
        int src = ei[e];
        int dst = ei[EE + e];
        float nrm = dinv[src] * ew[e] * dinv[dst];
        int pos = atomicAdd(&cursor[dst], 1);
        csr[pos] = make_uint2((uint)src, __float_as_uint(nrm));
    }
}

// ---------------- one-time weight transpose + bf16 convert ----------------

__global__ __launch_bounds__(256) void k_wcvt(const float* __restrict__ W,
                                              const float* __restrict__ W1,
                                              const float* __restrict__ W2,
                                              ushort* __restrict__ WTb,
                                              ushort* __restrict__ W1Tb,
                                              ushort* __restrict__ W2Tb) {
    int i = blockIdx.x * 256 + threadIdx.x;
    if (i < 16384) {
        int n = i >> 7, k = i & 127;
        WTb[i] = f2b(W[k * 128 + n]);
    } else if (i < 16384 + 65536) {
        int j = i - 16384;
        int f = j >> 7, k = j & 127;
        W1Tb[j] = f2b(W1[k * 512 + f]);
    } else {
        int j = i - 16384 - 65536;
        int jj = j >> 9, f = j & 511;
        W2Tb[j] = f2b(W2[f * 128 + jj]);
    }
}

// ---------------- x -> bf16 ----------------

__global__ __launch_bounds__(256) void k_xb(const float* __restrict__ x,
                                            ushort* __restrict__ xb) {
    long i = (long)blockIdx.x * 256 + threadIdx.x;   // float4 units, NN*32 total
    float4 v = ((const float4*)x)[i];
    ushort4 o;
    o.x = f2b(v.x); o.y = f2b(v.y); o.z = f2b(v.z); o.w = f2b(v.w);
    ((ushort4*)xb)[i] = o;
}

// ---------------- gather: agg[n] = dinv[n]^2*x~[n] + sum_e norm*x~[src]  (bf16 out) ----------------
// 32 nodes per block, 8 sequential nodes per wave, lane = 2 features, unroll-4.

__global__ __launch_bounds__(256) void k_gather(const ushort* __restrict__ xb,
                                                const float* __restrict__ dinv,
                                                const int* __restrict__ start,
                                                const uint2* __restrict__ csr,
                                                ushort* __restrict__ aggx) {
    int t = threadIdx.x;
    int wv = t >> 6, l = t & 63;
    const uint* xbu = (const uint*)xb;
    uint* aggu = (uint*)aggx;

    for (int k = 0; k < 8; ++k) {
        int node = blockIdx.x * 32 + wv * 8 + k;   // grid = NN/32 -> always < NN
        int e0 = start[node], e1 = start[node + 1];
        float a0 = 0.f, a1 = 0.f;
        int i = e0;
        for (; i + 4 <= e1; i += 4) {
            uint2 r0 = csr[i], r1 = csr[i + 1], r2 = csr[i + 2], r3 = csr[i + 3];
            uint h0 = xbu[r0.x * 64 + l];
            uint h1 = xbu[r1.x * 64 + l];
            uint h2 = xbu[r2.x * 64 + l];
            uint h3 = xbu[r3.x * 64 + l];
            float n0 = __uint_as_float(r0.y), n1 = __uint_as_float(r1.y);
            float n2 = __uint_as_float(r2.y), n3 = __uint_as_float(r3.y);
            a0 = fmaf(n0, b2f((ushort)(h0 & 0xFFFF)), a0);
            a1 = fmaf(n0, b2f((ushort)(h0 >> 16)), a1);
            a0 = fmaf(n1, b2f((ushort)(h1 & 0xFFFF)), a0);
            a1 = fmaf(n1, b2f((ushort)(h1 >> 16)), a1);
            a0 = fmaf(n2, b2f((ushort)(h2 & 0xFFFF)), a0);
            a1 = fmaf(n2, b2f((ushort)(h2 >> 16)), a1);
            a0 = fmaf(n3, b2f((ushort)(h3 & 0xFFFF)), a0);
            a1 = fmaf(n3, b2f((ushort)(h3 >> 16)), a1);
        }
        for (; i < e1; ++i) {
            uint2 r0 = csr[i];
            uint h0 = xbu[r0.x * 64 + l];
            float n0 = __uint_as_float(r0.y);
            a0 = fmaf(n0, b2f((ushort)(h0 & 0xFFFF)), a0);
            a1 = fmaf(n0, b2f((ushort)(h0 >> 16)), a1);
        }
        float dv = dinv[node];
        float sl = dv * dv;
        uint hs = xbu[node * 64 + l];
        a0 = fmaf(sl, b2f((ushort)(hs & 0xFFFF)), a0);
        a1 = fmaf(sl, b2f((ushort)(hs >> 16)), a1);
        aggu[node * 64 + l] = (uint)f2b(a0) | ((uint)f2b(a1) << 16);
    }
}

// ---------------- conv GEMM: y = x + agg @ W + b, BN1 stats fused ----------------
// 64 rows/block, 4 waves: rw=wv&1 (32-row half), jw=wv>>1 (64-feature half).
// Swapped MFMA (verified in k_mlp GEMM2): acc = mfma(W-frag, agg-frag)
//   -> 4 regs = 4 consecutive output features at jb, row = lr.

__global__ __launch_bounds__(256) void k_conv(const float* __restrict__ x,
                                              const ushort* __restrict__ aggx,
                                              const ushort* __restrict__ WTb,
                                              const float* __restrict__ b,
                                              float* __restrict__ y,
                                              float* __restrict__ stats1) {
    __shared__ __align__(16) ushort xt[64][136];
    __shared__ __align__(16) ushort wt[128][136];
    int t = threadIdx.x;
    int row0 = blockIdx.x * 64;

    for (int i = t; i < 2048; i += 256) {
        int r = i >> 4, c8 = (i & 15) << 3;
        *(uint4*)&wt[r][c8] = ((const uint4*)WTb)[i];
    }
    for (int i = t; i < 1024; i += 256) {
        int r = i >> 4, c8 = (i & 15) << 3;
        int gr = row0 + r;
        uint4 v = make_uint4(0u, 0u, 0u, 0u);
        if (gr < NN) v = ((const uint4*)aggx)[(long)gr * 16 + (i & 15)];
        *(uint4*)&xt[r][c8] = v;
    }
    __syncthreads();

    int wv = t >> 6, l = t & 63;
    int lr = l & 15, lg = l >> 4;
    int rw = wv & 1, jw = wv >> 1;

    f32x4 z4 = {0.f, 0.f, 0.f, 0.f};
    f32x4 acc[4][2];
#pragma unroll
    for (int jt = 0; jt < 4; ++jt)
#pragma unroll
        for (int rt = 0; rt < 2; ++rt) acc[jt][rt] = z4;

#pragma unroll
    for (int ks = 0; ks < 4; ++ks) {
        bf16x8 qR0 = *(const bf16x8*)&xt[rw * 32 + lr][ks * 32 + lg * 8];
        bf16x8 qR1 = *(const bf16x8*)&xt[rw * 32 + 16 + lr][ks * 32 + lg * 8];
#pragma unroll
        for (int jt = 0; jt < 4; ++jt) {
            bf16x8 pW = *(const bf16x8*)&wt[jw * 64 + jt * 16 + lr][ks * 32 + lg * 8];
            acc[jt][0] = __builtin_amdgcn_mfma_f32_16x16x32_bf16(pW, qR0, acc[jt][0], 0, 0, 0);
            acc[jt][1] = __builtin_amdgcn_mfma_f32_16x16x32_bf16(pW, qR1, acc[jt][1], 0, 0, 0);
        }
    }

    // epilogue: y = x + acc + b (float4), BN1 partials
    float sj[4][4], qj[4][4];
#pragma unroll
    for (int jt = 0; jt < 4; ++jt)
#pragma unroll
        for (int g = 0; g < 4; ++g) { sj[jt][g] = 0.f; qj[jt][g] = 0.f; }

#pragma unroll
    for (int jt = 0; jt < 4; ++jt) {
        int jb = jw * 64 + jt * 16 + lg * 4;
        float4 bv = *(const float4*)&b[jb];
#pragma unroll
        for (int rt = 0; rt < 2; ++rt) {
            int rloc = rw * 32 + rt * 16 + lr;
            int r = row0 + rloc;
            if (r < NN) {
                float4 xv = *(const float4*)&x[(long)r * 128 + jb];
                float z0 = xv.x + acc[jt][rt][0] + bv.x;
                float z1 = xv.y + acc[jt][rt][1] + bv.y;
                float z2 = xv.z + acc[jt][rt][2] + bv.z;
                float z3 = xv.w + acc[jt][rt][3] + bv.w;
                *(float4*)&y[(long)r * 128 + jb] = make_float4(z0, z1, z2, z3);
                sj[jt][0] += z0; sj[jt][1] += z1; sj[jt][2] += z2; sj[jt][3] += z3;
                qj[jt][0] += z0 * z0; qj[jt][1] += z1 * z1; qj[jt][2] += z2 * z2; qj[jt][3] += z3 * z3;
            }
        }
    }
#pragma unroll
    for (int jt = 0; jt < 4; ++jt)
#pragma unroll
        for (int g = 0; g < 4; ++g) {
#pragma unroll
            for (int d = 1; d < 16; d <<= 1) {
                sj[jt][g] += __shfl_xor(sj[jt][g], d);
                qj[jt][g] += __shfl_xor(qj[jt][g], d);
            }
        }
    __syncthreads();   // xt reads done; reuse as reduction buffer
    float* redS = (float*)&xt[0][0];    // [4][128]
    float* redQ = redS + 512;           // [4][128]
    if (lr == 0) {
#pragma unroll
        for (int jt = 0; jt < 4; ++jt)
#pragma unroll
            for (int g = 0; g < 4; ++g) {
                int j = jw * 64 + jt * 16 + lg * 4 + g;
                redS[wv * 128 + j] = sj[jt][g];
                redQ[wv * 128 + j] = qj[jt][g];
            }
    }
    __syncthreads();
    if (t < 128) {
        int w0 = (t >> 6) * 2;
        atomicAdd(&stats1[t], redS[w0 * 128 + t] + redS[(w0 + 1) * 128 + t]);
        atomicAdd(&stats1[128 + t], redQ[w0 * 128 + t] + redQ[(w0 + 1) * 128 + t]);
    }
}

// ---------------- BN finalize + affine ----------------

__global__ __launch_bounds__(128) void k_bn_fin(const float* __restrict__ stats,
                                                const float* __restrict__ gamma,
                                                const float* __restrict__ beta,
                                                float* __restrict__ ac) {
    int c = threadIdx.x;
    float mu = stats[c] * (1.0f / NN);
    float var = stats[128 + c] * (1.0f / NN) - mu * mu;
    float a = gamma[c] * rsqrtf(var + EPSV);
    ac[c] = a;
    ac[128 + c] = beta[c] - mu * a;
}

__global__ __launch_bounds__(256) void k_affine(float* __restrict__ v,
                                                const float* __restrict__ ac) {
    long i = (long)blockIdx.x * 256 + threadIdx.x;   // float4 units
    int c4i = (int)(i & 31);
    float4 a = ((const float4*)ac)[c4i];
    float4 cc = ((const float4*)(ac + 128))[c4i];
    float4 v4 = ((float4*)v)[i];
    v4.x = a.x * v4.x + cc.x;
    v4.y = a.y * v4.y + cc.y;
    v4.z = a.z * v4.z + cc.z;
    v4.w = a.w * v4.w + cc.w;
    ((float4*)v)[i] = v4;
}

// ---------------- fused MLP via MFMA (2x blocking + swapped GEMM2) ----------------

__global__ __launch_bounds__(256) void k_mlp(const float* __restrict__ y,
                                             const float* __restrict__ ac1,
                                             const ushort* __restrict__ W1Tb,
                                             const float* __restrict__ b1,
                                             const ushort* __restrict__ W2Tb,
                                             const float* __restrict__ b2,
                                             float* __restrict__ out,
                                             float* __restrict__ stats2) {
    __shared__ __align__(16) ushort xt[64][136];
    __shared__ __align__(16) ushort ht[64][136];
    __shared__ __align__(16) ushort wc[128][136];
    int t = threadIdx.x;
    int row0 = blockIdx.x * 64;

    for (int i = t; i < 2048; i += 256) {
        int r = i >> 5, c4i = i & 31;
        int gr = row0 + r;
        float4 v = make_float4(0.f, 0.f, 0.f, 0.f);
        if (gr < NN) v = ((const float4*)y)[(long)gr * 32 + c4i];
        float4 a = ((const float4*)ac1)[c4i];
        float4 cc = ((const float4*)(ac1 + 128))[c4i];
        ushort4 o;
        o.x = f2b(a.x * v.x + cc.x);
        o.y = f2b(a.y * v.y + cc.y);
        o.z = f2b(a.z * v.z + cc.z);
        o.w = f2b(a.w * v.w + cc.w);
        *(ushort4*)&xt[r][c4i << 2] = o;
    }

    int wv = t >> 6, l = t & 63;
    int lr = l & 15, lg = l >> 4;
    int rw = wv & 1;    // 32-row half
    int jw = wv >> 1;   // 64-col half

    f32x4 z4 = {0.f, 0.f, 0.f, 0.f};
    f32x4 acc[4][2];    // [jt][rt]
#pragma unroll
    for (int jt = 0; jt < 4; ++jt)
#pragma unroll
        for (int rt = 0; rt < 2; ++rt) acc[jt][rt] = z4;

    for (int ch = 0; ch < 4; ++ch) {
        __syncthreads();   // wc reuse (and xt staging at ch=0)
        for (int i = t; i < 2048; i += 256) {
            int r = i >> 4, c8 = (i & 15) << 3;
            *(uint4*)&wc[r][c8] = ((const uint4*)W1Tb)[ch * 2048 + i];
        }
        __syncthreads();

        // GEMM1: hidden(32r x 64f) = relu(x1 @ W1c + b1c)
        f32x4 hacc[4][2];  // [ft][rt]
#pragma unroll
        for (int ft = 0; ft < 4; ++ft)
#pragma unroll
            for (int rt = 0; rt < 2; ++rt) hacc[ft][rt] = z4;
#pragma unroll
        for (int ks = 0; ks < 4; ++ks) {
            bf16x8 aR0 = *(const bf16x8*)&xt[rw * 32 + lr][ks * 32 + lg * 8];
            bf16x8 aR1 = *(const bf16x8*)&xt[rw * 32 + 16 + lr][ks * 32 + lg * 8];
#pragma unroll
            for (int ft = 0; ft < 4; ++ft) {
                bf16x8 bW = *(const bf16x8*)&wc[jw * 64 + ft * 16 + lr][ks * 32 + lg * 8];
                hacc[ft][0] = __builtin_amdgcn_mfma_f32_16x16x32_bf16(aR0, bW, hacc[ft][0], 0, 0, 0);
                hacc[ft][1] = __builtin_amdgcn_mfma_f32_16x16x32_bf16(aR1, bW, hacc[ft][1], 0, 0, 0);
            }
        }
#pragma unroll
        for (int ft = 0; ft < 4; ++ft) {
            float b1v = b1[ch * 128 + jw * 64 + ft * 16 + lr];
#pragma unroll
            for (int rt = 0; rt < 2; ++rt)
#pragma unroll
                for (int rg = 0; rg < 4; ++rg)
                    ht[rw * 32 + rt * 16 + lg * 4 + rg][jw * 64 + ft * 16 + lr] =
                        f2b(fmaxf(hacc[ft][rt][rg] + b1v, 0.f));
        }
        __syncthreads();   // all ht written, wc free

        for (int i = t; i < 2048; i += 256) {
            int r = i >> 4, c8i = i & 15;
            *(uint4*)&wc[r][c8i << 3] = ((const uint4*)W2Tb)[r * 64 + ch * 16 + c8i];
        }
        __syncthreads();

        // GEMM2 swapped: acc(j x r) += W2c-rows x ht-rows
#pragma unroll
        for (int ks = 0; ks < 4; ++ks) {
            bf16x8 qR0 = *(const bf16x8*)&ht[rw * 32 + lr][ks * 32 + lg * 8];
            bf16x8 qR1 = *(const bf16x8*)&ht[rw * 32 + 16 + lr][ks * 32 + lg * 8];
#pragma unroll
            for (int jt = 0; jt < 4; ++jt) {
                bf16x8 pW = *(const bf16x8*)&wc[jw * 64 + jt * 16 + lr][ks * 32 + lg * 8];
                acc[jt][0] = __builtin_amdgcn_mfma_f32_16x16x32_bf16(pW, qR0, acc[jt][0], 0, 0, 0);
                acc[jt][1] = __builtin_amdgcn_mfma_f32_16x16x32_bf16(pW, qR1, acc[jt][1], 0, 0, 0);
            }
        }
    }

    // epilogue: z = x1 + x2 + b2 (float4 stores), BN2 partials
    float sj[4][4], qj[4][4];
#pragma unroll
    for (int jt = 0; jt < 4; ++jt)
#pragma unroll
        for (int g = 0; g < 4; ++g) { sj[jt][g] = 0.f; qj[jt][g] = 0.f; }

#pragma unroll
    for (int jt = 0; jt < 4; ++jt) {
        int jb = jw * 64 + jt * 16 + lg * 4;
        float4 b2v = *(const float4*)&b2[jb];
#pragma unroll
        for (int rt = 0; rt < 2; ++rt) {
            int rloc = rw * 32 + rt * 16 + lr;
            int r = row0 + rloc;
            ushort4 xv = *(const ushort4*)&xt[rloc][jb];
            float z0 = b2f(xv.x) + acc[jt][rt][0] + b2v.x;
            float z1 = b2f(xv.y) + acc[jt][rt][1] + b2v.y;
            float z2 = b2f(xv.z) + acc[jt][rt][2] + b2v.z;
            float z3 = b2f(xv.w) + acc[jt][rt][3] + b2v.w;
            if (r < NN) {
                *(float4*)&out[(long)r * 128 + jb] = make_float4(z0, z1, z2, z3);
                sj[jt][0] += z0; sj[jt][1] += z1; sj[jt][2] += z2; sj[jt][3] += z3;
                qj[jt][0] += z0 * z0; qj[jt][1] += z1 * z1; qj[jt][2] += z2 * z2; qj[jt][3] += z3 * z3;
            }
        }
    }
#pragma unroll
    for (int jt = 0; jt < 4; ++jt)
#pragma unroll
        for (int g = 0; g < 4; ++g) {
#pragma unroll
            for (int d = 1; d < 16; d <<= 1) {
                sj[jt][g] += __shfl_xor(sj[jt][g], d);
                qj[jt][g] += __shfl_xor(qj[jt][g], d);
            }
        }
    __syncthreads();   // ht reads done; reuse as reduction buffer
    float* redS = (float*)&ht[0][0];    // [4][128]
    float* redQ = redS + 512;           // [4][128]
    if (lr == 0) {
#pragma unroll
        for (int jt = 0; jt < 4; ++jt)
#pragma unroll
            for (int g = 0; g < 4; ++g) {
                int j = jw * 64 + jt * 16 + lg * 4 + g;
                redS[wv * 128 + j] = sj[jt][g];
                redQ[wv * 128 + j] = qj[jt][g];
            }
    }
    __syncthreads();
    if (t < 128) {
        int w0 = (t >> 6) * 2;   // the two waves owning this j-half
        atomicAdd(&stats2[t], redS[w0 * 128 + t] + redS[(w0 + 1) * 128 + t]);
        atomicAdd(&stats2[128 + t], redQ[w0 * 128 + t] + redQ[(w0 + 1) * 128 + t]);
    }
}

// ---------------- launch ----------------

extern "C" void kernel_launch(void* const* d_in, const int* in_sizes, int n_in,
                              void* d_out, int out_size, void* d_ws, size_t ws_size,
                              hipStream_t stream) {
    const float* x     = (const float*)d_in[0];
    const int*   ei    = (const int*)d_in[1];
    const float* ew    = (const float*)d_in[2];
    const float* W     = (const float*)d_in[3];
    const float* b     = (const float*)d_in[4];
    const float* gamma = (const float*)d_in[5];
    const float* beta  = (const float*)d_in[6];
    const float* W1    = (const float*)d_in[7];
    const float* b1    = (const float*)d_in[8];
    const float* W2    = (const float*)d_in[9];
    const float* b2    = (const float*)d_in[10];
    float* out = (float*)d_out;
    float* ws  = (float*)d_ws;

    float* deg    = ws;                              // NN
    float* dinv   = ws + NN;                         // NN
    float* stats1 = ws + 2 * NN;                     // 256
    float* ac1    = stats1 + 256;                    // 256
    float* stats2 = ac1 + 256;                       // 256
    float* ac2    = stats2 + 256;                    // 256
    ushort* xb    = (ushort*)(ws + 2 * NN + 1024);   // NN*128 bf16
    ushort* WTb   = xb + (long)NN * 128;             // 16384
    ushort* W1Tb  = WTb + 16384;                     // 65536
    ushort* W2Tb  = W1Tb + 65536;                    // 65536
    float*  fend  = ws + 2 * NN + 1024 + (long)NN * 64 + 73728;
    int*   cnt    = (int*)fend;                      // NN
    int*   start  = cnt + NN;                        // NN+1
    int*   cursor = start + NN + 1;                  // NN
    int*   bsum   = cursor + NN;                     // SCB
    int*   bbase  = bsum + SCB;                      // SCB
    uint2* csr    = (uint2*)(((uintptr_t)(bbase + SCB) + 7) & ~(uintptr_t)7);  // EE records
    ushort* aggx  = (ushort*)(csr + EE);             // NN*128 bf16
    float* y      = out;                             // x1 lives in d_out

    int nb = (NN + 63) / 64;   // 1563

    k_init<<<(NN + 255) / 256, 256, 0, stream>>>(deg, cnt, stats1, stats2);
    k_edge_deg<<<EE / 256, 256, 0, stream>>>(ei, ew, deg, cnt);
    k_dinv<<<(NN + 255) / 256, 256, 0, stream>>>(deg, dinv);
    k_scan_part<<<SCB, 256, 0, stream>>>(cnt, bsum);
    k_scan_base<<<1, 128, 0, stream>>>(bsum, bbase, start);
    k_scan_fin<<<SCB, 256, 0, stream>>>(cnt, bbase, start, cursor);
    k_fill<<<EE / 256, 256, 0, stream>>>(ei, ew, dinv, cursor, csr);
    k_wcvt<<<576, 256, 0, stream>>>(W, W1, W2, WTb, W1Tb, W2Tb);
    k_xb<<<(NN * 32) / 256, 256, 0, stream>>>(x, xb);
    k_gather<<<NN / 32, 256, 0, stream>>>(xb, dinv, start, csr, aggx);
    k_conv<<<nb, 256, 0, stream>>>(x, aggx, WTb, b, y, stats1);
    k_bn_fin<<<1, 128, 0, stream>>>(stats1, gamma, beta, ac1);
    k_mlp<<<nb, 256, 0, stream>>>(y, ac1, W1Tb, b1, W2Tb, b2, out, stats2);
    k_bn_fin<<<1, 128, 0, stream>>>(stats2, gamma, beta, ac2);
    k_affine<<<(NN * 32) / 256, 256, 0, stream>>>(out, ac2);
}

// Round 8
// 447.961 us; speedup vs baseline: 4.0173x; 1.1849x over previous
//
#include <hip/hip_runtime.h>

#define NN 100000
#define EE 1600000
#define DD 128
#define FFD 512
#define EPSV 1e-5f

#define SCB 98   // scan blocks: ceil(100000/1024)

typedef __attribute__((ext_vector_type(8))) short bf16x8;
typedef __attribute__((ext_vector_type(4))) float f32x4;
typedef unsigned long long ull;

__device__ __forceinline__ ushort f2b(float f) {          // fp32 -> bf16 RNE
    uint u = __float_as_uint(f);
    return (ushort)((u + 0x7FFF + ((u >> 16) & 1)) >> 16);
}
__device__ __forceinline__ float b2f(ushort u) {
    return __uint_as_float(((uint)u) << 16);
}

// ---------------- init: pk=0, stats=0 ----------------

__global__ __launch_bounds__(256) void k_init(ull* pk, float* s1, float* s2) {
    int i = blockIdx.x * 256 + threadIdx.x;
    if (i < NN) pk[i] = 0ULL;
    if (blockIdx.x == 0) { s1[threadIdx.x] = 0.f; s2[threadIdx.x] = 0.f; }
}

// ---------------- edge pass: ONE packed 64-bit atomic per edge ----------------
// hi32 = count, lo32 = sum(ew) in 24-bit fixed point (max degree ~50 << 256 overflow bound)

__global__ __launch_bounds__(256) void k_edge_deg(const int* __restrict__ ei,
                                                  const float* __restrict__ ew,
                                                  ull* __restrict__ pk) {
    int e = blockIdx.x * 256 + threadIdx.x;
    if (e < EE) {
        int dst = ei[EE + e];
        uint fx = (uint)(ew[e] * 16777216.0f + 0.5f);
        atomicAdd(&pk[dst], (1ULL << 32) | (ull)fx);
    }
}

// ---------------- scan part 1: block sums; unpack pk -> cnt, dinv ----------------

__global__ __launch_bounds__(256) void k_scan_part(const ull* __restrict__ pk,
                                                   int* __restrict__ cnt,
                                                   float* __restrict__ dinv,
                                                   int* __restrict__ bsum) {
    __shared__ int red[4];
    int b = blockIdx.x, t = threadIdx.x;
    int base = b * 1024 + t * 4;
    int s = 0;
#pragma unroll
    for (int j = 0; j < 4; ++j) {
        int i = base + j;
        if (i < NN) {
            ull v = pk[i];
            int c = (int)(v >> 32);
            cnt[i] = c;
            dinv[i] = rsqrtf(1.0f + (float)(uint)(v & 0xFFFFFFFFu) * (1.0f / 16777216.0f));
            s += c;
        }
    }
#pragma unroll
    for (int d = 1; d < 64; d <<= 1) s += __shfl_xor(s, d);
    if ((t & 63) == 0) red[t >> 6] = s;
    __syncthreads();
    if (t == 0) bsum[b] = red[0] + red[1] + red[2] + red[3];
}

__global__ __launch_bounds__(128) void k_scan_base(int* __restrict__ bsum,
                                                   int* __restrict__ bbase,
                                                   int* __restrict__ start) {
    if (threadIdx.x == 0) {
        int run = 0;
        for (int i = 0; i < SCB; ++i) { bbase[i] = run; run += bsum[i]; }
        start[NN] = run;   // == EE
    }
}

__global__ __launch_bounds__(256) void k_scan_fin(const int* __restrict__ cnt,
                                                  const int* __restrict__ bbase,
                                                  int* __restrict__ start,
                                                  int* __restrict__ cursor) {
    __shared__ int ts[256];
    int b = blockIdx.x, t = threadIdx.x;
    int base = b * 1024 + t * 4;
    int v[4];
    int s = 0;
#pragma unroll
    for (int j = 0; j < 4; ++j) {
        int i = base + j;
        v[j] = (i < NN) ? cnt[i] : 0;
        s += v[j];
    }
    ts[t] = s;
    __syncthreads();
    for (int d = 1; d < 256; d <<= 1) {
        int add = (t >= d) ? ts[t - d] : 0;
        __syncthreads();
        ts[t] += add;
        __syncthreads();
    }
    int run = bbase[b] + ts[t] - s;   // exclusive offset for this thread
#pragma unroll
    for (int j = 0; j < 4; ++j) {
        int i = base + j;
        if (i < NN) {
            start[i] = run;
            cursor[i] = run;
            run += v[j];
        }
    }
}

// ---------------- fill CSR records (src, norm) bucketed by dst ----------------

__global__ __launch_bounds__(256) void k_fill(const int* __restrict__ ei,
                                              const float* __restrict__ ew,
                                              const float* __restrict__ dinv,
                                              int* __restrict__ cursor,
                                              uint2* __restrict__ csr) {
    int e = blockIdx.x * 256 + threadIdx.x;
    if (e < EE) {
        int src = ei[e];
        int dst = ei[EE + e];
        float nrm = dinv[src] * ew[e] * dinv[dst];
        int pos = atomicAdd(&cursor[dst], 1);
        csr[pos] = make_uint2((uint)src, __float_as_uint(nrm));
    }
}

// ---------------- one-time weight transpose + bf16 convert ----------------

__global__ __launch_bounds__(256) void k_wcvt(const float* __restrict__ W,
                                              const float* __restrict__ W1,
                                              const float* __restrict__ W2,
                                              ushort* __restrict__ WTb,
                                              ushort* __restrict__ W1Tb,
                                              ushort* __restrict__ W2Tb) {
    int i = blockIdx.x * 256 + threadIdx.x;
    if (i < 16384) {
        int n = i >> 7, k = i & 127;
        WTb[i] = f2b(W[k * 128 + n]);
    } else if (i < 16384 + 65536) {
        int j = i - 16384;
        int f = j >> 7, k = j & 127;
        W1Tb[j] = f2b(W1[k * 512 + f]);
    } else {
        int j = i - 16384 - 65536;
        int jj = j >> 9, f = j & 511;
        W2Tb[j] = f2b(W2[f * 128 + jj]);
    }
}

// ---------------- x -> bf16 ----------------

__global__ __launch_bounds__(256) void k_xb(const float* __restrict__ x,
                                            ushort* __restrict__ xb) {
    long i = (long)blockIdx.x * 256 + threadIdx.x;   // float4 units, NN*32 total
    float4 v = ((const float4*)x)[i];
    ushort4 o;
    o.x = f2b(v.x); o.y = f2b(v.y); o.z = f2b(v.z); o.w = f2b(v.w);
    ((ushort4*)xb)[i] = o;
}

// ---------------- gather: agg[n] = dinv[n]^2*x~[n] + sum_e norm*x~[src]  (bf16 out) ----------------
// 32 nodes per block, 8 sequential nodes per wave, lane = 2 features, unroll-8.

__global__ __launch_bounds__(256) void k_gather(const ushort* __restrict__ xb,
                                                const float* __restrict__ dinv,
                                                const int* __restrict__ start,
                                                const uint2* __restrict__ csr,
                                                ushort* __restrict__ aggx) {
    int t = threadIdx.x;
    int wv = t >> 6, l = t & 63;
    const uint* xbu = (const uint*)xb;
    uint* aggu = (uint*)aggx;

    for (int k = 0; k < 8; ++k) {
        int node = blockIdx.x * 32 + wv * 8 + k;   // grid = NN/32 -> always < NN
        int e0 = start[node], e1 = start[node + 1];
        float a0 = 0.f, a1 = 0.f;
        int i = e0;
        for (; i + 8 <= e1; i += 8) {
            uint2 rr[8];
            uint hh[8];
#pragma unroll
            for (int u = 0; u < 8; ++u) rr[u] = csr[i + u];
#pragma unroll
            for (int u = 0; u < 8; ++u) hh[u] = xbu[rr[u].x * 64 + l];
#pragma unroll
            for (int u = 0; u < 8; ++u) {
                float n = __uint_as_float(rr[u].y);
                a0 = fmaf(n, b2f((ushort)(hh[u] & 0xFFFF)), a0);
                a1 = fmaf(n, b2f((ushort)(hh[u] >> 16)), a1);
            }
        }
        if (i + 4 <= e1) {
            uint2 rr[4];
            uint hh[4];
#pragma unroll
            for (int u = 0; u < 4; ++u) rr[u] = csr[i + u];
#pragma unroll
            for (int u = 0; u < 4; ++u) hh[u] = xbu[rr[u].x * 64 + l];
#pragma unroll
            for (int u = 0; u < 4; ++u) {
                float n = __uint_as_float(rr[u].y);
                a0 = fmaf(n, b2f((ushort)(hh[u] & 0xFFFF)), a0);
                a1 = fmaf(n, b2f((ushort)(hh[u] >> 16)), a1);
            }
            i += 4;
        }
        for (; i < e1; ++i) {
            uint2 r0 = csr[i];
            uint h0 = xbu[r0.x * 64 + l];
            float n0 = __uint_as_float(r0.y);
            a0 = fmaf(n0, b2f((ushort)(h0 & 0xFFFF)), a0);
            a1 = fmaf(n0, b2f((ushort)(h0 >> 16)), a1);
        }
        float dv = dinv[node];
        float sl = dv * dv;
        uint hs = xbu[node * 64 + l];
        a0 = fmaf(sl, b2f((ushort)(hs & 0xFFFF)), a0);
        a1 = fmaf(sl, b2f((ushort)(hs >> 16)), a1);
        aggu[node * 64 + l] = (uint)f2b(a0) | ((uint)f2b(a1) << 16);
    }
}

// ---------------- conv GEMM: y = x + agg @ W + b, BN1 stats fused ----------------

__global__ __launch_bounds__(256) void k_conv(const float* __restrict__ x,
                                              const ushort* __restrict__ aggx,
                                              const ushort* __restrict__ WTb,
                                              const float* __restrict__ b,
                                              float* __restrict__ y,
                                              float* __restrict__ stats1) {
    __shared__ __align__(16) ushort xt[64][136];
    __shared__ __align__(16) ushort wt[128][136];
    int t = threadIdx.x;
    int row0 = blockIdx.x * 64;

    for (int i = t; i < 2048; i += 256) {
        int r = i >> 4, c8 = (i & 15) << 3;
        *(uint4*)&wt[r][c8] = ((const uint4*)WTb)[i];
    }
    for (int i = t; i < 1024; i += 256) {
        int r = i >> 4, c8 = (i & 15) << 3;
        int gr = row0 + r;
        uint4 v = make_uint4(0u, 0u, 0u, 0u);
        if (gr < NN) v = ((const uint4*)aggx)[(long)gr * 16 + (i & 15)];
        *(uint4*)&xt[r][c8] = v;
    }
    __syncthreads();

    int wv = t >> 6, l = t & 63;
    int lr = l & 15, lg = l >> 4;
    int rw = wv & 1, jw = wv >> 1;

    f32x4 z4 = {0.f, 0.f, 0.f, 0.f};
    f32x4 acc[4][2];
#pragma unroll
    for (int jt = 0; jt < 4; ++jt)
#pragma unroll
        for (int rt = 0; rt < 2; ++rt) acc[jt][rt] = z4;

#pragma unroll
    for (int ks = 0; ks < 4; ++ks) {
        bf16x8 qR0 = *(const bf16x8*)&xt[rw * 32 + lr][ks * 32 + lg * 8];
        bf16x8 qR1 = *(const bf16x8*)&xt[rw * 32 + 16 + lr][ks * 32 + lg * 8];
#pragma unroll
        for (int jt = 0; jt < 4; ++jt) {
            bf16x8 pW = *(const bf16x8*)&wt[jw * 64 + jt * 16 + lr][ks * 32 + lg * 8];
            acc[jt][0] = __builtin_amdgcn_mfma_f32_16x16x32_bf16(pW, qR0, acc[jt][0], 0, 0, 0);
            acc[jt][1] = __builtin_amdgcn_mfma_f32_16x16x32_bf16(pW, qR1, acc[jt][1], 0, 0, 0);
        }
    }

    // epilogue: y = x + acc + b (float4), BN1 partials
    float sj[4][4], qj[4][4];
#pragma unroll
    for (int jt = 0; jt < 4; ++jt)
#pragma unroll
        for (int g = 0; g < 4; ++g) { sj[jt][g] = 0.f; qj[jt][g] = 0.f; }

#pragma unroll
    for (int jt = 0; jt < 4; ++jt) {
        int jb = jw * 64 + jt * 16 + lg * 4;
        float4 bv = *(const float4*)&b[jb];
#pragma unroll
        for (int rt = 0; rt < 2; ++rt) {
            int rloc = rw * 32 + rt * 16 + lr;
            int r = row0 + rloc;
            if (r < NN) {
                float4 xv = *(const float4*)&x[(long)r * 128 + jb];
                float z0 = xv.x + acc[jt][rt][0] + bv.x;
                float z1 = xv.y + acc[jt][rt][1] + bv.y;
                float z2 = xv.z + acc[jt][rt][2] + bv.z;
                float z3 = xv.w + acc[jt][rt][3] + bv.w;
                *(float4*)&y[(long)r * 128 + jb] = make_float4(z0, z1, z2, z3);
                sj[jt][0] += z0; sj[jt][1] += z1; sj[jt][2] += z2; sj[jt][3] += z3;
                qj[jt][0] += z0 * z0; qj[jt][1] += z1 * z1; qj[jt][2] += z2 * z2; qj[jt][3] += z3 * z3;
            }
        }
    }
#pragma unroll
    for (int jt = 0; jt < 4; ++jt)
#pragma unroll
        for (int g = 0; g < 4; ++g) {
#pragma unroll
            for (int d = 1; d < 16; d <<= 1) {
                sj[jt][g] += __shfl_xor(sj[jt][g], d);
                qj[jt][g] += __shfl_xor(qj[jt][g], d);
            }
        }
    __syncthreads();   // xt reads done; reuse as reduction buffer
    float* redS = (float*)&xt[0][0];    // [4][128]
    float* redQ = redS + 512;           // [4][128]
    if (lr == 0) {
#pragma unroll
        for (int jt = 0; jt < 4; ++jt)
#pragma unroll
            for (int g = 0; g < 4; ++g) {
                int j = jw * 64 + jt * 16 + lg * 4 + g;
                redS[wv * 128 + j] = sj[jt][g];
                redQ[wv * 128 + j] = qj[jt][g];
            }
    }
    __syncthreads();
    if (t < 128) {
        int w0 = (t >> 6) * 2;
        atomicAdd(&stats1[t], redS[w0 * 128 + t] + redS[(w0 + 1) * 128 + t]);
        atomicAdd(&stats1[128 + t], redQ[w0 * 128 + t] + redQ[(w0 + 1) * 128 + t]);
    }
}

// ---------------- BN finalize + affine ----------------

__global__ __launch_bounds__(128) void k_bn_fin(const float* __restrict__ stats,
                                                const float* __restrict__ gamma,
                                                const float* __restrict__ beta,
                                                float* __restrict__ ac) {
    int c = threadIdx.x;
    float mu = stats[c] * (1.0f / NN);
    float var = stats[128 + c] * (1.0f / NN) - mu * mu;
    float a = gamma[c] * rsqrtf(var + EPSV);
    ac[c] = a;
    ac[128 + c] = beta[c] - mu * a;
}

__global__ __launch_bounds__(256) void k_affine(float* __restrict__ v,
                                                const float* __restrict__ ac) {
    long i = (long)blockIdx.x * 256 + threadIdx.x;   // float4 units
    int c4i = (int)(i & 31);
    float4 a = ((const float4*)ac)[c4i];
    float4 cc = ((const float4*)(ac + 128))[c4i];
    float4 v4 = ((float4*)v)[i];
    v4.x = a.x * v4.x + cc.x;
    v4.y = a.y * v4.y + cc.y;
    v4.z = a.z * v4.z + cc.z;
    v4.w = a.w * v4.w + cc.w;
    ((float4*)v)[i] = v4;
}

// ---------------- fused MLP via MFMA (2x blocking + swapped GEMM2) ----------------

__global__ __launch_bounds__(256) void k_mlp(const float* __restrict__ y,
                                             const float* __restrict__ ac1,
                                             const ushort* __restrict__ W1Tb,
                                             const float* __restrict__ b1,
                                             const ushort* __restrict__ W2Tb,
                                             const float* __restrict__ b2,
                                             float* __restrict__ out,
                                             float* __restrict__ stats2) {
    __shared__ __align__(16) ushort xt[64][136];
    __shared__ __align__(16) ushort ht[64][136];
    __shared__ __align__(16) ushort wc[128][136];
    int t = threadIdx.x;
    int row0 = blockIdx.x * 64;

    for (int i = t; i < 2048; i += 256) {
        int r = i >> 5, c4i = i & 31;
        int gr = row0 + r;
        float4 v = make_float4(0.f, 0.f, 0.f, 0.f);
        if (gr < NN) v = ((const float4*)y)[(long)gr * 32 + c4i];
        float4 a = ((const float4*)ac1)[c4i];
        float4 cc = ((const float4*)(ac1 + 128))[c4i];
        ushort4 o;
        o.x = f2b(a.x * v.x + cc.x);
        o.y = f2b(a.y * v.y + cc.y);
        o.z = f2b(a.z * v.z + cc.z);
        o.w = f2b(a.w * v.w + cc.w);
        *(ushort4*)&xt[r][c4i << 2] = o;
    }

    int wv = t >> 6, l = t & 63;
    int lr = l & 15, lg = l >> 4;
    int rw = wv & 1;    // 32-row half
    int jw = wv >> 1;   // 64-col half

    f32x4 z4 = {0.f, 0.f, 0.f, 0.f};
    f32x4 acc[4][2];    // [jt][rt]
#pragma unroll
    for (int jt = 0; jt < 4; ++jt)
#pragma unroll
        for (int rt = 0; rt < 2; ++rt) acc[jt][rt] = z4;

    for (int ch = 0; ch < 4; ++ch) {
        __syncthreads();   // wc reuse (and xt staging at ch=0)
        for (int i = t; i < 2048; i += 256) {
            int r = i >> 4, c8 = (i & 15) << 3;
            *(uint4*)&wc[r][c8] = ((const uint4*)W1Tb)[ch * 2048 + i];
        }
        __syncthreads();

        // GEMM1: hidden(32r x 64f) = relu(x1 @ W1c + b1c)
        f32x4 hacc[4][2];  // [ft][rt]
#pragma unroll
        for (int ft = 0; ft < 4; ++ft)
#pragma unroll
            for (int rt = 0; rt < 2; ++rt) hacc[ft][rt] = z4;
#pragma unroll
        for (int ks = 0; ks < 4; ++ks) {
            bf16x8 aR0 = *(const bf16x8*)&xt[rw * 32 + lr][ks * 32 + lg * 8];
            bf16x8 aR1 = *(const bf16x8*)&xt[rw * 32 + 16 + lr][ks * 32 + lg * 8];
#pragma unroll
            for (int ft = 0; ft < 4; ++ft) {
                bf16x8 bW = *(const bf16x8*)&wc[jw * 64 + ft * 16 + lr][ks * 32 + lg * 8];
                hacc[ft][0] = __builtin_amdgcn_mfma_f32_16x16x32_bf16(aR0, bW, hacc[ft][0], 0, 0, 0);
                hacc[ft][1] = __builtin_amdgcn_mfma_f32_16x16x32_bf16(aR1, bW, hacc[ft][1], 0, 0, 0);
            }
        }
#pragma unroll
        for (int ft = 0; ft < 4; ++ft) {
            float b1v = b1[ch * 128 + jw * 64 + ft * 16 + lr];
#pragma unroll
            for (int rt = 0; rt < 2; ++rt)
#pragma unroll
                for (int rg = 0; rg < 4; ++rg)
                    ht[rw * 32 + rt * 16 + lg * 4 + rg][jw * 64 + ft * 16 + lr] =
                        f2b(fmaxf(hacc[ft][rt][rg] + b1v, 0.f));
        }
        __syncthreads();   // all ht written, wc free

        for (int i = t; i < 2048; i += 256) {
            int r = i >> 4, c8i = i & 15;
            *(uint4*)&wc[r][c8i << 3] = ((const uint4*)W2Tb)[r * 64 + ch * 16 + c8i];
        }
        __syncthreads();

        // GEMM2 swapped: acc(j x r) += W2c-rows x ht-rows
#pragma unroll
        for (int ks = 0; ks < 4; ++ks) {
            bf16x8 qR0 = *(const bf16x8*)&ht[rw * 32 + lr][ks * 32 + lg * 8];
            bf16x8 qR1 = *(const bf16x8*)&ht[rw * 32 + 16 + lr][ks * 32 + lg * 8];
#pragma unroll
            for (int jt = 0; jt < 4; ++jt) {
                bf16x8 pW = *(const bf16x8*)&wc[jw * 64 + jt * 16 + lr][ks * 32 + lg * 8];
                acc[jt][0] = __builtin_amdgcn_mfma_f32_16x16x32_bf16(pW, qR0, acc[jt][0], 0, 0, 0);
                acc[jt][1] = __builtin_amdgcn_mfma_f32_16x16x32_bf16(pW, qR1, acc[jt][1], 0, 0, 0);
            }
        }
    }

    // epilogue: z = x1 + x2 + b2 (float4 stores), BN2 partials
    float sj[4][4], qj[4][4];
#pragma unroll
    for (int jt = 0; jt < 4; ++jt)
#pragma unroll
        for (int g = 0; g < 4; ++g) { sj[jt][g] = 0.f; qj[jt][g] = 0.f; }

#pragma unroll
    for (int jt = 0; jt < 4; ++jt) {
        int jb = jw * 64 + jt * 16 + lg * 4;
        float4 b2v = *(const float4*)&b2[jb];
#pragma unroll
        for (int rt = 0; rt < 2; ++rt) {
            int rloc = rw * 32 + rt * 16 + lr;
            int r = row0 + rloc;
            ushort4 xv = *(const ushort4*)&xt[rloc][jb];
            float z0 = b2f(xv.x) + acc[jt][rt][0] + b2v.x;
            float z1 = b2f(xv.y) + acc[jt][rt][1] + b2v.y;
            float z2 = b2f(xv.z) + acc[jt][rt][2] + b2v.z;
            float z3 = b2f(xv.w) + acc[jt][rt][3] + b2v.w;
            if (r < NN) {
                *(float4*)&out[(long)r * 128 + jb] = make_float4(z0, z1, z2, z3);
                sj[jt][0] += z0; sj[jt][1] += z1; sj[jt][2] += z2; sj[jt][3] += z3;
                qj[jt][0] += z0 * z0; qj[jt][1] += z1 * z1; qj[jt][2] += z2 * z2; qj[jt][3] += z3 * z3;
            }
        }
    }
#pragma unroll
    for (int jt = 0; jt < 4; ++jt)
#pragma unroll
        for (int g = 0; g < 4; ++g) {
#pragma unroll
            for (int d = 1; d < 16; d <<= 1) {
                sj[jt][g] += __shfl_xor(sj[jt][g], d);
                qj[jt][g] += __shfl_xor(qj[jt][g], d);
            }
        }
    __syncthreads();   // ht reads done; reuse as reduction buffer
    float* redS = (float*)&ht[0][0];    // [4][128]
    float* redQ = redS + 512;           // [4][128]
    if (lr == 0) {
#pragma unroll
        for (int jt = 0; jt < 4; ++jt)
#pragma unroll
            for (int g = 0; g < 4; ++g) {
                int j = jw * 64 + jt * 16 + lg * 4 + g;
                redS[wv * 128 + j] = sj[jt][g];
                redQ[wv * 128 + j] = qj[jt][g];
            }
    }
    __syncthreads();
    if (t < 128) {
        int w0 = (t >> 6) * 2;   // the two waves owning this j-half
        atomicAdd(&stats2[t], redS[w0 * 128 + t] + redS[(w0 + 1) * 128 + t]);
        atomicAdd(&stats2[128 + t], redQ[w0 * 128 + t] + redQ[(w0 + 1) * 128 + t]);
    }
}

// ---------------- launch ----------------

extern "C" void kernel_launch(void* const* d_in, const int* in_sizes, int n_in,
                              void* d_out, int out_size, void* d_ws, size_t ws_size,
                              hipStream_t stream) {
    const float* x     = (const float*)d_in[0];
    const int*   ei    = (const int*)d_in[1];
    const float* ew    = (const float*)d_in[2];
    const float* W     = (const float*)d_in[3];
    const float* b     = (const float*)d_in[4];
    const float* gamma = (const float*)d_in[5];
    const float* beta  = (const float*)d_in[6];
    const float* W1    = (const float*)d_in[7];
    const float* b1    = (const float*)d_in[8];
    const float* W2    = (const float*)d_in[9];
    const float* b2    = (const float*)d_in[10];
    float* out = (float*)d_out;
    float* ws  = (float*)d_ws;

    ull*   pk     = (ull*)ws;                        // NN (8B each = 2*NN floats)
    float* dinv   = ws + 2 * NN;                     // NN
    float* stats1 = ws + 3 * NN;                     // 256
    float* ac1    = stats1 + 256;                    // 256
    float* stats2 = ac1 + 256;                       // 256
    float* ac2    = stats2 + 256;                    // 256
    ushort* xb    = (ushort*)(ws + 3 * NN + 1024);   // NN*128 bf16
    ushort* WTb   = xb + (long)NN * 128;             // 16384
    ushort* W1Tb  = WTb + 16384;                     // 65536
    ushort* W2Tb  = W1Tb + 65536;                    // 65536
    float*  fend  = ws + 3 * NN + 1024 + (long)NN * 64 + 73728;
    int*   cnt    = (int*)fend;                      // NN
    int*   start  = cnt + NN;                        // NN+1
    int*   cursor = start + NN + 1;                  // NN
    int*   bsum   = cursor + NN;                     // SCB
    int*   bbase  = bsum + SCB;                      // SCB
    uint2* csr    = (uint2*)(((uintptr_t)(bbase + SCB) + 7) & ~(uintptr_t)7);  // EE records
    ushort* aggx  = (ushort*)(csr + EE);             // NN*128 bf16
    float* y      = out;                             // x1 lives in d_out

    int nb = (NN + 63) / 64;   // 1563

    k_init<<<(NN + 255) / 256, 256, 0, stream>>>(pk, stats1, stats2);
    k_edge_deg<<<EE / 256, 256, 0, stream>>>(ei, ew, pk);
    k_scan_part<<<SCB, 256, 0, stream>>>(pk, cnt, dinv, bsum);
    k_scan_base<<<1, 128, 0, stream>>>(bsum, bbase, start);
    k_scan_fin<<<SCB, 256, 0, stream>>>(cnt, bbase, start, cursor);
    k_fill<<<EE / 256, 256, 0, stream>>>(ei, ew, dinv, cursor, csr);
    k_wcvt<<<576, 256, 0, stream>>>(W, W1, W2, WTb, W1Tb, W2Tb);
    k_xb<<<(NN * 32) / 256, 256, 0, stream>>>(x, xb);
    k_gather<<<NN / 32, 256, 0, stream>>>(xb, dinv, start, csr, aggx);
    k_conv<<<nb, 256, 0, stream>>>(x, aggx, WTb, b, y, stats1);
    k_bn_fin<<<1, 128, 0, stream>>>(stats1, gamma, beta, ac1);
    k_mlp<<<nb, 256, 0, stream>>>(y, ac1, W1Tb, b1, W2Tb, b2, out, stats2);
    k_bn_fin<<<1, 128, 0, stream>>>(stats2, gamma, beta, ac2);
    k_affine<<<(NN * 32) / 256, 256, 0, stream>>>(out, ac2);
}